// Round 1
// 845.583 us; speedup vs baseline: 1.1021x; 1.1021x over previous
//
#include <hip/hip_runtime.h>

typedef _Float16 f16;
typedef _Float16 f16x8 __attribute__((ext_vector_type(8)));
typedef float f32x4 __attribute__((ext_vector_type(4)));

#define REGION_DIM 144
#define LLM_DIM 3584
#define NUM_HEADS 4
#define HEAD_DIM 36
#define HEAD_PAD 64      // head_dim padded to 64 -> 4 heads = 256 cols
#define QK_COLS 256      // NUM_HEADS * HEAD_PAD
#define KPAD_REGION 160  // region_dim padded to multiple of 32
#define V_HEAD 896
#define LN_EPS 1e-5f

// ---------------------------------------------------------------------------
// async global->LDS, 16B per lane (m97 pattern)
__device__ __forceinline__ void gl_lds16(const f16* g, f16* l)
{
    __builtin_amdgcn_global_load_lds(
        (const __attribute__((address_space(1))) unsigned int*)g,
        (__attribute__((address_space(3))) unsigned int*)l, 16, 0, 0);
}

#define S_BARRIER() do { asm volatile("" ::: "memory"); __builtin_amdgcn_s_barrier(); asm volatile("" ::: "memory"); } while (0)
#define WAIT_LGKM0() asm volatile("s_waitcnt lgkmcnt(0)" ::: "memory")
#define SCHED_FENCE() __builtin_amdgcn_sched_barrier(0)

// ---------------------------------------------------------------------------
// fp32 -> fp16 convert with optional column zero-pad. grid: (ceil(Cout/256), R)
__global__ void k_convert_pad(const float* __restrict__ in, f16* __restrict__ out,
                              int Cin, int Cout)
{
    int r = blockIdx.y;
    int c = blockIdx.x * 256 + threadIdx.x;
    if (c >= Cout) return;
    float v = (c < Cin) ? in[(long)r * Cin + c] : 0.f;
    out[(long)r * Cout + c] = (f16)v;
}

// ---------------------------------------------------------------------------
// transpose+convert: out[b][c][r] = (r<R && c<C ? in[b][r][c] : 0), out [Cpad][Rpad]
// block (32,8), grid (Cpad/32, ceil(Rpad/32), batch)
__global__ void k_transpose(const float* __restrict__ in, f16* __restrict__ out,
                            int R, int C, int Rpad, int Cpad,
                            long in_bstride, long out_bstride)
{
    __shared__ float tile[32][33];
    const float* ip = in + (long)blockIdx.z * in_bstride;
    f16* op = out + (long)blockIdx.z * out_bstride;
    int r0 = blockIdx.y * 32, c0 = blockIdx.x * 32;
    int tx = threadIdx.x, ty = threadIdx.y;
#pragma unroll
    for (int i = 0; i < 32; i += 8) {
        int r = r0 + ty + i, c = c0 + tx;
        tile[ty + i][tx] = (r < R && c < C) ? ip[(long)r * C + c] : 0.f;
    }
    __syncthreads();
#pragma unroll
    for (int i = 0; i < 32; i += 8) {
        int c = c0 + ty + i, r = r0 + tx;
        if (c < Cpad && r < Rpad) op[(long)c * Rpad + r] = (f16)tile[tx][ty + i];
    }
}

// ---------------------------------------------------------------------------
// Build head-padded transposed QK weight: outW[h*64+kk][e] = (kk<36 && e<E) ? w[e][h*36+kk] : 0
// also padded bias. grid (ceil(Epad/256), 256)
__global__ void k_headpad_w(const float* __restrict__ w, const float* __restrict__ b,
                            f16* __restrict__ outW, float* __restrict__ outB,
                            int E, int Epad)
{
    int hp = blockIdx.y;
    int h = hp >> 6, kk = hp & 63;
    int d = h * HEAD_DIM + kk;
    bool valid = (kk < HEAD_DIM);
    int e = blockIdx.x * 256 + threadIdx.x;
    if (e < Epad) {
        float v = (valid && e < E) ? w[(long)e * REGION_DIM + d] : 0.f;
        outW[(long)hp * Epad + e] = (f16)v;
    }
    if (blockIdx.x == 0 && threadIdx.x == 0) outB[hp] = valid ? b[d] : 0.f;
}

// ---------------------------------------------------------------------------
enum { EPI_F16_EXPSCALE = 0,  // store exp(v*scale)   (softmax numerator, no max-sub)
       EPI_F16_BIASROW  = 1,  // store v + bias[row]
       EPI_F16_DIVROW   = 2,  // store v / bias[row]  (softmax denominator)
       EPI_F32_BIASCOL  = 3,  // store fp32 v + bias[col]
       EPI_F16_BIASCOL  = 4 };

// ---------------------------------------------------------------------------
// Templated MFMA GEMM (128x128 tile, 4 waves) — kept for small/odd-shaped GEMMs.
template <int EPI>
__global__ __launch_bounds__(256, 2)
void gemm_f16(const f16* __restrict__ A, int lda, long sAz,
              const f16* __restrict__ Bt, int ldb, long sBz,
              void* __restrict__ Cv, int ldc, long sCz,
              const float* __restrict__ bias, long sbz, float scale, int K)
{
    __shared__ __align__(16) f16 sA[128 * 32];
    __shared__ __align__(16) f16 sB[128 * 32];
    const int tid = threadIdx.x;
    const int z = blockIdx.z;
    A += (long)z * sAz;
    Bt += (long)z * sBz;
    if (bias) bias += (long)z * sbz;

    const int gx = gridDim.x, gy = gridDim.y;
    int pid = blockIdx.y * gx + blockIdx.x;
    const int GROUP = 8;
    int span = GROUP * gx;
    int gid = pid / span;
    int y0 = gid * GROUP;
    int gsz = (gy - y0 < GROUP) ? (gy - y0) : GROUP;
    int rem = pid - gid * span;
    const int by = y0 + rem % gsz;
    const int bx = rem / gsz;
    const int m0 = by * 128, n0 = bx * 128;

    const int w = tid >> 6, l = tid & 63;
    const int wu = __builtin_amdgcn_readfirstlane(w);
    const int wr = w >> 1, wc = w & 1;

    f32x4 acc[4][4] = {};

    const int srow = tid >> 2;
    const int scol = (tid & 3) * 8;
    const f16* Ag = A + (long)(m0 + srow) * lda + scol;
    const f16* Bg = Bt + (long)(n0 + srow) * ldb + scol;
    f16* sA0 = sA + wu * 512;
    f16* sA1 = sA + 2048 + wu * 512;
    f16* sB0 = sB + wu * 512;
    f16* sB1 = sB + 2048 + wu * 512;
    const int qk = (l >> 4) * 8;
    const int fr = l & 15;

    for (int k0 = 0; k0 < K; k0 += 32) {
        __syncthreads();
        gl_lds16(Ag + k0, sA0);
        gl_lds16(Ag + (long)64 * lda + k0, sA1);
        gl_lds16(Bg + k0, sB0);
        gl_lds16(Bg + (long)64 * ldb + k0, sB1);
        __syncthreads();

        f16x8 af[4], bf[4];
#pragma unroll
        for (int mt = 0; mt < 4; mt++)
            af[mt] = *(const f16x8*)&sA[(wr * 64 + mt * 16 + fr) * 32 + qk];
#pragma unroll
        for (int nt = 0; nt < 4; nt++)
            bf[nt] = *(const f16x8*)&sB[(wc * 64 + nt * 16 + fr) * 32 + qk];
#pragma unroll
        for (int mt = 0; mt < 4; mt++)
#pragma unroll
            for (int nt = 0; nt < 4; nt++)
                acc[mt][nt] = __builtin_amdgcn_mfma_f32_16x16x32_f16(af[mt], bf[nt], acc[mt][nt], 0, 0, 0);
    }

    const int q4 = (l >> 4) * 4;
    float bc[4];
#pragma unroll
    for (int nt = 0; nt < 4; nt++) {
        if constexpr (EPI == EPI_F16_BIASCOL || EPI == EPI_F32_BIASCOL)
            bc[nt] = bias[n0 + wc * 64 + nt * 16 + fr];
        else
            bc[nt] = 0.f;
    }
#pragma unroll
    for (int mt = 0; mt < 4; mt++)
#pragma unroll
        for (int r = 0; r < 4; r++) {
            int row = m0 + wr * 64 + mt * 16 + q4 + r;
            float rowv = 0.f;
            if constexpr (EPI == EPI_F16_BIASROW) rowv = bias[row];
            if constexpr (EPI == EPI_F16_DIVROW) rowv = 1.f / bias[row];
#pragma unroll
            for (int nt = 0; nt < 4; nt++) {
                int col = n0 + wc * 64 + nt * 16 + fr;
                float v = acc[mt][nt][r];
                if constexpr (EPI == EPI_F16_EXPSCALE) {
                    ((f16*)Cv + (long)z * sCz)[(long)row * ldc + col] = (f16)__expf(v * scale);
                } else if constexpr (EPI == EPI_F16_BIASROW) {
                    ((f16*)Cv + (long)z * sCz)[(long)row * ldc + col] = (f16)(v + rowv);
                } else if constexpr (EPI == EPI_F16_DIVROW) {
                    ((f16*)Cv + (long)z * sCz)[(long)row * ldc + col] = (f16)(v * rowv);
                } else if constexpr (EPI == EPI_F16_BIASCOL) {
                    ((f16*)Cv + (long)z * sCz)[(long)row * ldc + col] = (f16)(v + bc[nt]);
                } else {
                    ((float*)Cv + (long)z * sCz)[(long)row * ldc + col] = v + bc[nt];
                }
            }
        }
}

// ---------------------------------------------------------------------------
// 256x256 / BK=64 / 8-wave / 8-phase counted-vmcnt GEMM (m201 template, plain HIP).
// C[M,N] = A[M,K] * Bt[N,K]^T + epilogue. Requires M%256==0, N%256==0, K%64==0.
//
// LDS (128 KiB, f16 units): buf p at p*32768; A halves at +0/+8192; B region
// at +16384 with halves +0/+8192. Half-tile = 128 rows x 64 cols f16 (16 KiB),
// staged by 2 global_load_lds x 512 lanes x 16B. LDS dest is linear; the
// T2 swizzle col^=(row&7)*16B is applied by inverse-permuting the per-lane
// GLOBAL source column (rule #21), and on the ds_read address.
//
// Per tile t (4 phases = quadrants (mh,nh) in order 00,01,11,10):
//   a: read af[mh0](8) + bf0(4); stage A1(t+1)->buf p^1
//   b: read bf1(4);              stage B1(t+1)->buf p^1
//   c: read af[mh1](8);          stage B0(t+2)->buf p   (B halves dead after b)
//   d: (no reads);               stage A0(t+2)->buf p   (A halves dead after c)
//   gate at end of d: vmcnt(4) -> all of tile t+1 landed, 2 half-tiles in flight.
template <int EPI>
__global__ __launch_bounds__(512, 2)
void gemm256_f16(const f16* __restrict__ A, int lda,
                 const f16* __restrict__ Bt, int ldb,
                 void* __restrict__ Cv, int ldc,
                 const float* __restrict__ bias, int K)
{
    __shared__ __align__(16) f16 sm[65536];   // 128 KiB
    f16* smf = sm;

    const int tid = threadIdx.x;
    const int l = tid & 63;

    // bijective XCD-chunk swizzle (m204), then column-major tile decompose
    const int gx = gridDim.x, gy = gridDim.y;
    int pid = blockIdx.y * gx + blockIdx.x;
    int nwg = gx * gy;
    int q = nwg >> 3, r8 = nwg & 7;
    int xcd = pid & 7, idx = pid >> 3;
    int swz = (xcd < r8) ? (xcd * (q + 1) + idx)
                         : (r8 * (q + 1) + (xcd - r8) * q + idx);
    const int by = swz % gy, bx = swz / gy;
    const int m0 = by * 256, n0 = bx * 256;

    const int wu = __builtin_amdgcn_readfirstlane(tid >> 6);  // wave 0..7
    const int wr = wu >> 2;        // M-half of block (2)
    const int wc = wu & 3;         // N-quarter of block (4)
    const int wst = wu * 512;      // per-wave LDS stage base (f16)

    // staging source: lane covers row (w*8 + l>>3) (+64*inst, +128*half),
    // col f16 = ((l&7)^(l>>3))*8  (inverse of read-side XOR swizzle)
    const int strow = wu * 8 + (l >> 3);
    const int stcol = ((l & 7) ^ (l >> 3)) * 8;
    const f16* Asrc = A + (size_t)(m0 + strow) * lda + stcol;
    const f16* Bsrc = Bt + (size_t)(n0 + strow) * ldb + stcol;

    // ds_read fragment addressing
    const int fr = l & 15;
    const int hi8 = (l >> 4) * 8;
    const int swl = (fr & 7) * 8;
    const int ca0 = hi8 ^ swl;            // K-slice 0, swizzled col (f16)
    const int ca1 = (32 + hi8) ^ swl;     // K-slice 1

    const int NT = K >> 6;

    f32x4 acc[8][4] = {};
    f16x8 af[4][2], bf0[2][2], bf1[2][2];

    // ---- prologue: tile0 (4 half-tiles) + B0(1), A0(1) ----
    gl_lds16(Asrc, smf + wst);
    gl_lds16(Asrc + (size_t)64 * lda, smf + 4096 + wst);
    gl_lds16(Bsrc, smf + 16384 + wst);
    gl_lds16(Bsrc + (size_t)64 * ldb, smf + 16384 + 4096 + wst);
    gl_lds16(Asrc + (size_t)128 * lda, smf + 8192 + wst);
    gl_lds16(Asrc + (size_t)192 * lda, smf + 8192 + 4096 + wst);
    gl_lds16(Bsrc + (size_t)128 * ldb, smf + 16384 + 8192 + wst);
    gl_lds16(Bsrc + (size_t)192 * ldb, smf + 16384 + 8192 + 4096 + wst);
    if (NT > 1) {
        gl_lds16(Bsrc + 64, smf + 32768 + 16384 + wst);
        gl_lds16(Bsrc + 64 + (size_t)64 * ldb, smf + 32768 + 16384 + 4096 + wst);
        gl_lds16(Asrc + 64, smf + 32768 + wst);
        gl_lds16(Asrc + 64 + (size_t)64 * lda, smf + 32768 + 4096 + wst);
        asm volatile("s_waitcnt vmcnt(4)" ::: "memory");
    } else {
        asm volatile("s_waitcnt vmcnt(0)" ::: "memory");
    }
    S_BARRIER();

#define MFMA16(MB, NB, BF)                                                            \
    _Pragma("unroll") for (int i = 0; i < 4; i++)                                     \
    _Pragma("unroll") for (int j = 0; j < 2; j++) {                                   \
        acc[MB + i][NB + j] = __builtin_amdgcn_mfma_f32_16x16x32_f16(                 \
            af[i][0], BF[j][0], acc[MB + i][NB + j], 0, 0, 0);                        \
        acc[MB + i][NB + j] = __builtin_amdgcn_mfma_f32_16x16x32_f16(                 \
            af[i][1], BF[j][1], acc[MB + i][NB + j], 0, 0, 0);                        \
    }

    for (int t = 0; t < NT; ++t) {
        const int p = t & 1;
        const f16* sAp = smf + (p << 15) + wr * 8192 + fr * 64;
        const f16* sBp = smf + (p << 15) + 16384 + wc * 4096 + fr * 64;

        // ---------- phase a: quadrant (0,0); stage A1(t+1) ----------
#pragma unroll
        for (int i = 0; i < 4; i++) {
            af[i][0] = *(const f16x8*)(sAp + i * 1024 + ca0);
            af[i][1] = *(const f16x8*)(sAp + i * 1024 + ca1);
        }
#pragma unroll
        for (int j = 0; j < 2; j++) {
            bf0[j][0] = *(const f16x8*)(sBp + j * 1024 + ca0);
            bf0[j][1] = *(const f16x8*)(sBp + j * 1024 + ca1);
        }
        if (t + 1 < NT) {
            const f16* s = Asrc + (size_t)128 * lda + (size_t)(t + 1) * 64;
            f16* d = smf + ((p ^ 1) << 15) + 8192 + wst;
            gl_lds16(s, d);
            gl_lds16(s + (size_t)64 * lda, d + 4096);
        }
        S_BARRIER();
        WAIT_LGKM0();
        SCHED_FENCE();
        __builtin_amdgcn_s_setprio(1);
        MFMA16(0, 0, bf0);
        __builtin_amdgcn_s_setprio(0);
        WAIT_LGKM0();
        S_BARRIER();

        // ---------- phase b: quadrant (0,1); stage B1(t+1) ----------
#pragma unroll
        for (int j = 0; j < 2; j++) {
            bf1[j][0] = *(const f16x8*)(sBp + 2048 + j * 1024 + ca0);
            bf1[j][1] = *(const f16x8*)(sBp + 2048 + j * 1024 + ca1);
        }
        if (t + 1 < NT) {
            const f16* s = Bsrc + (size_t)128 * ldb + (size_t)(t + 1) * 64;
            f16* d = smf + ((p ^ 1) << 15) + 16384 + 8192 + wst;
            gl_lds16(s, d);
            gl_lds16(s + (size_t)64 * ldb, d + 4096);
        }
        S_BARRIER();
        WAIT_LGKM0();
        SCHED_FENCE();
        __builtin_amdgcn_s_setprio(1);
        MFMA16(0, 2, bf1);
        __builtin_amdgcn_s_setprio(0);
        WAIT_LGKM0();
        S_BARRIER();

        // ---------- phase c: quadrant (1,1); stage B0(t+2) ----------
#pragma unroll
        for (int i = 0; i < 4; i++) {
            af[i][0] = *(const f16x8*)(sAp + 4096 + i * 1024 + ca0);
            af[i][1] = *(const f16x8*)(sAp + 4096 + i * 1024 + ca1);
        }
        if (t + 2 < NT) {
            const f16* s = Bsrc + (size_t)(t + 2) * 64;
            f16* d = smf + (p << 15) + 16384 + wst;
            gl_lds16(s, d);
            gl_lds16(s + (size_t)64 * ldb, d + 4096);
        }
        S_BARRIER();
        WAIT_LGKM0();
        SCHED_FENCE();
        __builtin_amdgcn_s_setprio(1);
        MFMA16(4, 2, bf1);
        __builtin_amdgcn_s_setprio(0);
        WAIT_LGKM0();
        S_BARRIER();

        // ---------- phase d: quadrant (1,0); stage A0(t+2); tile gate ----------
        if (t + 2 < NT) {
            const f16* s = Asrc + (size_t)(t + 2) * 64;
            f16* d = smf + (p << 15) + wst;
            gl_lds16(s, d);
            gl_lds16(s + (size_t)64 * lda, d + 4096);
        }
        S_BARRIER();
        __builtin_amdgcn_s_setprio(1);
        MFMA16(4, 0, bf0);
        __builtin_amdgcn_s_setprio(0);
        if (t + 2 < NT) {
            asm volatile("s_waitcnt vmcnt(4)" ::: "memory");
        } else if (t + 1 < NT) {
            asm volatile("s_waitcnt vmcnt(0)" ::: "memory");
        }
        S_BARRIER();
    }
#undef MFMA16

    // ---- epilogue: C/D layout col=lane&15, row=(lane>>4)*4+reg ----
    const int q4 = (l >> 4) * 4;
    float bc[4];
#pragma unroll
    for (int nt = 0; nt < 4; nt++) {
        if constexpr (EPI == EPI_F16_BIASCOL || EPI == EPI_F32_BIASCOL)
            bc[nt] = bias[n0 + wc * 64 + nt * 16 + fr];
        else
            bc[nt] = 0.f;
    }
#pragma unroll
    for (int mt = 0; mt < 8; mt++)
#pragma unroll
        for (int r = 0; r < 4; r++) {
            int row = m0 + wr * 128 + mt * 16 + q4 + r;
            float rowv = 0.f;
            if constexpr (EPI == EPI_F16_BIASROW) rowv = bias[row];
            if constexpr (EPI == EPI_F16_DIVROW) rowv = 1.f / bias[row];
#pragma unroll
            for (int nt = 0; nt < 4; nt++) {
                int col = n0 + wc * 64 + nt * 16 + fr;
                float v = acc[mt][nt][r];
                if constexpr (EPI == EPI_F16_BIASROW) {
                    ((f16*)Cv)[(size_t)row * ldc + col] = (f16)(v + rowv);
                } else if constexpr (EPI == EPI_F16_DIVROW) {
                    ((f16*)Cv)[(size_t)row * ldc + col] = (f16)(v * rowv);
                } else if constexpr (EPI == EPI_F16_BIASCOL) {
                    ((f16*)Cv)[(size_t)row * ldc + col] = (f16)(v + bc[nt]);
                } else {
                    ((float*)Cv)[(size_t)row * ldc + col] = v + bc[nt];
                }
            }
        }
}

// ---------------------------------------------------------------------------
// row sums of exp-scores: lsum[z][n] = sum_m P[z][n][m]. grid (N, HB), block 256.
__global__ void k_rowsum(const f16* __restrict__ P, float* __restrict__ lsum,
                         long hstride)
{
    const f16x8* p8 = (const f16x8*)(P + (long)blockIdx.y * hstride + (long)blockIdx.x * 4096);
    int t = threadIdx.x, w = t >> 6, l = t & 63;
    f16x8 a = p8[t], b = p8[256 + t];
    float s = 0.f;
#pragma unroll
    for (int j = 0; j < 8; j++) s += (float)a[j] + (float)b[j];
#pragma unroll
    for (int o = 32; o; o >>= 1) s += __shfl_xor(s, o);
    __shared__ float red[4];
    if (l == 0) red[w] = s;
    __syncthreads();
    if (t == 0)
        lsum[(long)blockIdx.y * gridDim.x + blockIdx.x] = red[0] + red[1] + red[2] + red[3];
}

// ---------------------------------------------------------------------------
// LayerNorm over 3584 cols of (ctx + resid), both f16, -> f16 out. grid N, block 256.
__global__ void k_layernorm(const f16* __restrict__ ctxp, const f16* __restrict__ resp,
                            const float* __restrict__ g, const float* __restrict__ be,
                            f16* __restrict__ out)
{
    long base = (long)blockIdx.x * LLM_DIM;
    const f16x8* c8 = (const f16x8*)(ctxp + base);
    const f16x8* r8 = (const f16x8*)(resp + base);
    int t = threadIdx.x, w = t >> 6, l = t & 63;
    bool has2 = t < 192;
    f16x8 a0 = c8[t], b0 = r8[t];
    f16x8 a1 = {}, b1 = {};
    if (has2) { a1 = c8[256 + t]; b1 = r8[256 + t]; }
    float v[16];
    float s = 0.f;
#pragma unroll
    for (int j = 0; j < 8; j++) { v[j] = (float)a0[j] + (float)b0[j]; s += v[j]; }
#pragma unroll
    for (int j = 0; j < 8; j++) v[8 + j] = (float)a1[j] + (float)b1[j];
    if (has2)
#pragma unroll
        for (int j = 0; j < 8; j++) s += v[8 + j];
#pragma unroll
    for (int o = 32; o; o >>= 1) s += __shfl_xor(s, o);
    __shared__ float r1[4];
    if (l == 0) r1[w] = s;
    __syncthreads();
    float mu = (r1[0] + r1[1] + r1[2] + r1[3]) * (1.f / LLM_DIM);
    float s2 = 0.f;
#pragma unroll
    for (int j = 0; j < 8; j++) { float d = v[j] - mu; s2 += d * d; }
    if (has2)
#pragma unroll
        for (int j = 8; j < 16; j++) { float d = v[j] - mu; s2 += d * d; }
#pragma unroll
    for (int o = 32; o; o >>= 1) s2 += __shfl_xor(s2, o);
    __shared__ float r2[4];
    if (l == 0) r2[w] = s2;
    __syncthreads();
    float var = (r2[0] + r2[1] + r2[2] + r2[3]) * (1.f / LLM_DIM);
    float inv = rsqrtf(var + LN_EPS);
    f16* op = out + base;
    f16x8 o0, o1;
#pragma unroll
    for (int j = 0; j < 8; j++) {
        int c = t * 8 + j;
        o0[j] = (f16)((v[j] - mu) * inv * g[c] + be[c]);
    }
    ((f16x8*)op)[t] = o0;
    if (has2) {
#pragma unroll
        for (int j = 0; j < 8; j++) {
            int c = (256 + t) * 8 + j;
            o1[j] = (f16)((v[8 + j] - mu) * inv * g[c] + be[c]);
        }
        ((f16x8*)op)[256 + t] = o1;
    }
}

// ---------------------------------------------------------------------------
extern "C" void kernel_launch(void* const* d_in, const int* in_sizes, int n_in,
                              void* d_out, int out_size, void* d_ws, size_t ws_size,
                              hipStream_t stream)
{
    const float* target  = (const float*)d_in[0];
    const float* source  = (const float*)d_in[1];
    const float* value   = (const float*)d_in[2];
    const float* wq_w    = (const float*)d_in[3];
    const float* wq_b    = (const float*)d_in[4];
    const float* wk_w    = (const float*)d_in[5];
    const float* wk_b    = (const float*)d_in[6];
    const float* wv_w    = (const float*)d_in[7];
    const float* wv_b    = (const float*)d_in[8];
    const float* resid_w = (const float*)d_in[9];
    const float* resid_b = (const float*)d_in[10];
    const float* out_w   = (const float*)d_in[11];
    const float* out_b   = (const float*)d_in[12];
    const float* ln_g    = (const float*)d_in[13];
    const float* ln_b    = (const float*)d_in[14];

    const int N = in_sizes[0] / REGION_DIM;  // 4096
    const int M = in_sizes[1] / LLM_DIM;     // 4096

    // ---- workspace: persistent ~149.9 MB + one 67.1 MB aliased union = 217 MB
    char* ws = (char*)d_ws;
    size_t off = 0;
    auto alloc = [&](size_t bytes) { void* p = ws + off; off += (bytes + 255) & ~(size_t)255; return p; };
    f16*   tgt16   = (f16*)alloc((size_t)N * KPAD_REGION * 2);
    f16*   residT  = (f16*)alloc((size_t)LLM_DIM * KPAD_REGION * 2); // [3584][160]
    f16*   outT    = (f16*)alloc((size_t)LLM_DIM * LLM_DIM * 2);     // [3584][3584]
    f16*   wqT     = (f16*)alloc((size_t)QK_COLS * KPAD_REGION * 2); // [256][160]
    float* biasK   = (float*)alloc(QK_COLS * 4);
    float* biasQ   = (float*)alloc(QK_COLS * 4);
    f16*   Qtmp    = (f16*)alloc((size_t)N * QK_COLS * 2);           // [N][256]
    f16*   Ktmp    = (f16*)alloc((size_t)M * QK_COLS * 2);           // [M][256]
    f16*   Vt      = (f16*)alloc((size_t)LLM_DIM * M * 2);           // [H*896][M]
    f16*   residbf = (f16*)alloc((size_t)N * LLM_DIM * 2);           // resid proj, f16
    f16*   ctx     = (f16*)alloc((size_t)N * LLM_DIM * 2);           // attn output, f16
    f16*   xln     = (f16*)alloc((size_t)N * LLM_DIM * 2);
    float* lsum    = (float*)alloc((size_t)2 * N * 4);               // [HB][N]
    const int HB = 2;
    char* U = (char*)alloc((size_t)HB * N * M * 2);                  // 67.1 MB
    f16* val16 = (f16*)U;
    f16* wvT   = (f16*)(U + (size_t)M * LLM_DIM * 2);
    f16* src16 = (f16*)U;
    f16* wkT   = (f16*)(U + (size_t)M * LLM_DIM * 2);
    f16* attnB = (f16*)U;
    (void)n_in; (void)out_size; (void)ws_size;

    dim3 tb(32, 8);

    // ---- phase 0: target-side prep ----
    k_convert_pad<<<dim3(1, N), 256, 0, stream>>>(target, tgt16, REGION_DIM, KPAD_REGION);
    k_transpose<<<dim3(LLM_DIM / 32, KPAD_REGION / 32, 1), tb, 0, stream>>>(
        resid_w, residT, REGION_DIM, LLM_DIM, KPAD_REGION, LLM_DIM, 0, 0);
    k_transpose<<<dim3(LLM_DIM / 32, LLM_DIM / 32, 1), tb, 0, stream>>>(
        out_w, outT, LLM_DIM, LLM_DIM, LLM_DIM, LLM_DIM, 0, 0);
    k_headpad_w<<<dim3(1, QK_COLS), 256, 0, stream>>>(wq_w, wq_b, wqT, biasQ, REGION_DIM, KPAD_REGION);

    gemm_f16<EPI_F16_BIASCOL><<<dim3(QK_COLS / 128, N / 128), 256, 0, stream>>>(
        tgt16, KPAD_REGION, 0, wqT, KPAD_REGION, 0, Qtmp, QK_COLS, 0, biasQ, 0, 1.f, KPAD_REGION);
    gemm_f16<EPI_F16_BIASCOL><<<dim3(LLM_DIM / 128, N / 128), 256, 0, stream>>>(
        tgt16, KPAD_REGION, 0, residT, KPAD_REGION, 0, residbf, LLM_DIM, 0, resid_b, 0, 1.f, KPAD_REGION);

    // ---- phase V: value projection (256^2 8-phase GEMM) ----
    k_convert_pad<<<dim3(LLM_DIM / 256, M), 256, 0, stream>>>(value, val16, LLM_DIM, LLM_DIM);
    k_transpose<<<dim3(V_HEAD / 32, LLM_DIM / 32, NUM_HEADS), tb, 0, stream>>>(
        wv_w, wvT, LLM_DIM, V_HEAD, LLM_DIM, V_HEAD, (long)LLM_DIM * V_HEAD, (long)V_HEAD * LLM_DIM);
    gemm256_f16<EPI_F16_BIASROW><<<dim3(M / 256, LLM_DIM / 256), 512, 0, stream>>>(
        wvT, LLM_DIM, val16, LLM_DIM, Vt, M, wv_b, LLM_DIM);

    // ---- phase K: key projection ----
    k_convert_pad<<<dim3(LLM_DIM / 256, M), 256, 0, stream>>>(source, src16, LLM_DIM, LLM_DIM);
    k_headpad_w<<<dim3(LLM_DIM / 256, QK_COLS), 256, 0, stream>>>(wk_w, wk_b, wkT, biasK, LLM_DIM, LLM_DIM);
    gemm_f16<EPI_F16_BIASCOL><<<dim3(QK_COLS / 128, M / 128), 256, 0, stream>>>(
        src16, LLM_DIM, 0, wkT, LLM_DIM, 0, Ktmp, QK_COLS, 0, biasK, 0, 1.f, LLM_DIM);

    // ---- phase A: attention, 2 heads at a time ----
    const float sc = 0.16666667f;  // 1/sqrt(36)
    for (int h0 = 0; h0 < NUM_HEADS; h0 += HB) {
        gemm_f16<EPI_F16_EXPSCALE><<<dim3(M / 128, N / 128, HB), 256, 0, stream>>>(
            Qtmp + h0 * HEAD_PAD, QK_COLS, HEAD_PAD,
            Ktmp + h0 * HEAD_PAD, QK_COLS, HEAD_PAD,
            attnB, M, (long)N * M, nullptr, 0, sc, HEAD_PAD);
        k_rowsum<<<dim3(N, HB), 256, 0, stream>>>(attnB, lsum, (long)N * M);
        gemm_f16<EPI_F16_DIVROW><<<dim3(V_HEAD / 128, N / 128, HB), 256, 0, stream>>>(
            attnB, M, (long)N * M,
            Vt + (size_t)h0 * V_HEAD * M, M, (long)V_HEAD * M,
            ctx + (size_t)h0 * V_HEAD, LLM_DIM, V_HEAD, lsum, N, 1.f, M);
    }

    // ---- epilogue: LayerNorm + output projection (256^2 8-phase GEMM) ----
    k_layernorm<<<N, 256, 0, stream>>>(ctx, residbf, ln_g, ln_b, xln);
    gemm256_f16<EPI_F32_BIASCOL><<<dim3(LLM_DIM / 256, N / 256), 512, 0, stream>>>(
        xln, LLM_DIM, outT, LLM_DIM, (float*)d_out, LLM_DIM, out_b, LLM_DIM);
}

// Round 2
// 845.470 us; speedup vs baseline: 1.1022x; 1.0001x over previous
//
#include <hip/hip_runtime.h>

typedef _Float16 f16;
typedef _Float16 f16x8 __attribute__((ext_vector_type(8)));
typedef float f32x4 __attribute__((ext_vector_type(4)));

#define REGION_DIM 144
#define LLM_DIM 3584
#define NUM_HEADS 4
#define HEAD_DIM 36
#define HEAD_PAD 64      // head_dim padded to 64 -> 4 heads = 256 cols
#define QK_COLS 256      // NUM_HEADS * HEAD_PAD
#define KPAD_REGION 160  // region_dim padded to multiple of 32
#define V_HEAD 896
#define LN_EPS 1e-5f

// ---------------------------------------------------------------------------
// async global->LDS, 16B per lane (m97 pattern)
__device__ __forceinline__ void gl_lds16(const f16* g, f16* l)
{
    __builtin_amdgcn_global_load_lds(
        (const __attribute__((address_space(1))) unsigned int*)g,
        (__attribute__((address_space(3))) unsigned int*)l, 16, 0, 0);
}

#define S_BARRIER() do { asm volatile("" ::: "memory"); __builtin_amdgcn_s_barrier(); asm volatile("" ::: "memory"); } while (0)
#define SCHED_FENCE() __builtin_amdgcn_sched_barrier(0)

// ---------------------------------------------------------------------------
// fp32 -> fp16 convert with optional column zero-pad. grid: (ceil(Cout/256), R)
__global__ void k_convert_pad(const float* __restrict__ in, f16* __restrict__ out,
                              int Cin, int Cout)
{
    int r = blockIdx.y;
    int c = blockIdx.x * 256 + threadIdx.x;
    if (c >= Cout) return;
    float v = (c < Cin) ? in[(long)r * Cin + c] : 0.f;
    out[(long)r * Cout + c] = (f16)v;
}

// ---------------------------------------------------------------------------
// transpose+convert: out[b][c][r] = (r<R && c<C ? in[b][r][c] : 0), out [Cpad][Rpad]
// block (32,8), grid (Cpad/32, ceil(Rpad/32), batch)
__global__ void k_transpose(const float* __restrict__ in, f16* __restrict__ out,
                            int R, int C, int Rpad, int Cpad,
                            long in_bstride, long out_bstride)
{
    __shared__ float tile[32][33];
    const float* ip = in + (long)blockIdx.z * in_bstride;
    f16* op = out + (long)blockIdx.z * out_bstride;
    int r0 = blockIdx.y * 32, c0 = blockIdx.x * 32;
    int tx = threadIdx.x, ty = threadIdx.y;
#pragma unroll
    for (int i = 0; i < 32; i += 8) {
        int r = r0 + ty + i, c = c0 + tx;
        tile[ty + i][tx] = (r < R && c < C) ? ip[(long)r * C + c] : 0.f;
    }
    __syncthreads();
#pragma unroll
    for (int i = 0; i < 32; i += 8) {
        int c = c0 + ty + i, r = r0 + tx;
        if (c < Cpad && r < Rpad) op[(long)c * Rpad + r] = (f16)tile[tx][ty + i];
    }
}

// ---------------------------------------------------------------------------
// Build head-padded transposed QK weight: outW[h*64+kk][e] = (kk<36 && e<E) ? w[e][h*36+kk] : 0
// also padded bias. grid (ceil(Epad/256), 256)
__global__ void k_headpad_w(const float* __restrict__ w, const float* __restrict__ b,
                            f16* __restrict__ outW, float* __restrict__ outB,
                            int E, int Epad)
{
    int hp = blockIdx.y;
    int h = hp >> 6, kk = hp & 63;
    int d = h * HEAD_DIM + kk;
    bool valid = (kk < HEAD_DIM);
    int e = blockIdx.x * 256 + threadIdx.x;
    if (e < Epad) {
        float v = (valid && e < E) ? w[(long)e * REGION_DIM + d] : 0.f;
        outW[(long)hp * Epad + e] = (f16)v;
    }
    if (blockIdx.x == 0 && threadIdx.x == 0) outB[hp] = valid ? b[d] : 0.f;
}

// ---------------------------------------------------------------------------
enum { EPI_F16_EXPSCALE = 0,  // store exp(v*scale)   (softmax numerator, no max-sub)
       EPI_F16_BIASROW  = 1,  // store v + bias[row]
       EPI_F16_DIVROW   = 2,  // store v / bias[row]  (softmax denominator)
       EPI_F32_BIASCOL  = 3,  // store fp32 v + bias[col]
       EPI_F16_BIASCOL  = 4 };

// ---------------------------------------------------------------------------
// Templated MFMA GEMM (128x128 tile, 4 waves) — kept for small/odd-shaped GEMMs.
template <int EPI>
__global__ __launch_bounds__(256, 2)
void gemm_f16(const f16* __restrict__ A, int lda, long sAz,
              const f16* __restrict__ Bt, int ldb, long sBz,
              void* __restrict__ Cv, int ldc, long sCz,
              const float* __restrict__ bias, long sbz, float scale, int K)
{
    __shared__ __align__(16) f16 sA[128 * 32];
    __shared__ __align__(16) f16 sB[128 * 32];
    const int tid = threadIdx.x;
    const int z = blockIdx.z;
    A += (long)z * sAz;
    Bt += (long)z * sBz;
    if (bias) bias += (long)z * sbz;

    const int gx = gridDim.x, gy = gridDim.y;
    int pid = blockIdx.y * gx + blockIdx.x;
    const int GROUP = 8;
    int span = GROUP * gx;
    int gid = pid / span;
    int y0 = gid * GROUP;
    int gsz = (gy - y0 < GROUP) ? (gy - y0) : GROUP;
    int rem = pid - gid * span;
    const int by = y0 + rem % gsz;
    const int bx = rem / gsz;
    const int m0 = by * 128, n0 = bx * 128;

    const int w = tid >> 6, l = tid & 63;
    const int wu = __builtin_amdgcn_readfirstlane(w);
    const int wr = w >> 1, wc = w & 1;

    f32x4 acc[4][4] = {};

    const int srow = tid >> 2;
    const int scol = (tid & 3) * 8;
    const f16* Ag = A + (long)(m0 + srow) * lda + scol;
    const f16* Bg = Bt + (long)(n0 + srow) * ldb + scol;
    f16* sA0 = sA + wu * 512;
    f16* sA1 = sA + 2048 + wu * 512;
    f16* sB0 = sB + wu * 512;
    f16* sB1 = sB + 2048 + wu * 512;
    const int qk = (l >> 4) * 8;
    const int fr = l & 15;

    for (int k0 = 0; k0 < K; k0 += 32) {
        __syncthreads();
        gl_lds16(Ag + k0, sA0);
        gl_lds16(Ag + (long)64 * lda + k0, sA1);
        gl_lds16(Bg + k0, sB0);
        gl_lds16(Bg + (long)64 * ldb + k0, sB1);
        __syncthreads();

        f16x8 af[4], bf[4];
#pragma unroll
        for (int mt = 0; mt < 4; mt++)
            af[mt] = *(const f16x8*)&sA[(wr * 64 + mt * 16 + fr) * 32 + qk];
#pragma unroll
        for (int nt = 0; nt < 4; nt++)
            bf[nt] = *(const f16x8*)&sB[(wc * 64 + nt * 16 + fr) * 32 + qk];
#pragma unroll
        for (int mt = 0; mt < 4; mt++)
#pragma unroll
            for (int nt = 0; nt < 4; nt++)
                acc[mt][nt] = __builtin_amdgcn_mfma_f32_16x16x32_f16(af[mt], bf[nt], acc[mt][nt], 0, 0, 0);
    }

    const int q4 = (l >> 4) * 4;
    float bc[4];
#pragma unroll
    for (int nt = 0; nt < 4; nt++) {
        if constexpr (EPI == EPI_F16_BIASCOL || EPI == EPI_F32_BIASCOL)
            bc[nt] = bias[n0 + wc * 64 + nt * 16 + fr];
        else
            bc[nt] = 0.f;
    }
#pragma unroll
    for (int mt = 0; mt < 4; mt++)
#pragma unroll
        for (int r = 0; r < 4; r++) {
            int row = m0 + wr * 64 + mt * 16 + q4 + r;
            float rowv = 0.f;
            if constexpr (EPI == EPI_F16_BIASROW) rowv = bias[row];
            if constexpr (EPI == EPI_F16_DIVROW) rowv = 1.f / bias[row];
#pragma unroll
            for (int nt = 0; nt < 4; nt++) {
                int col = n0 + wc * 64 + nt * 16 + fr;
                float v = acc[mt][nt][r];
                if constexpr (EPI == EPI_F16_EXPSCALE) {
                    ((f16*)Cv + (long)z * sCz)[(long)row * ldc + col] = (f16)__expf(v * scale);
                } else if constexpr (EPI == EPI_F16_BIASROW) {
                    ((f16*)Cv + (long)z * sCz)[(long)row * ldc + col] = (f16)(v + rowv);
                } else if constexpr (EPI == EPI_F16_DIVROW) {
                    ((f16*)Cv + (long)z * sCz)[(long)row * ldc + col] = (f16)(v * rowv);
                } else if constexpr (EPI == EPI_F16_BIASCOL) {
                    ((f16*)Cv + (long)z * sCz)[(long)row * ldc + col] = (f16)(v + bc[nt]);
                } else {
                    ((float*)Cv + (long)z * sCz)[(long)row * ldc + col] = v + bc[nt];
                }
            }
        }
}

// ---------------------------------------------------------------------------
// 256x256 / BK=64 / 8-wave GEMM, decoupled-phase schedule (r2).
// C[M,N] = A[M,K] * Bt[N,K]^T + epilogue. Requires M%256==0, N%256==0, K%64==0.
//
// LDS (128 KiB, f16 units): buf p at p*32768; A halves at +0/+8192; B region
// at +16384 with halves +0/+8192. Half-tile = 128 rows x 64 cols f16 (16 KiB).
// T2 swizzle col^=(row&7)*16B applied via inverse-permuted GLOBAL source col
// (rule #21) + swizzled ds_read address. Bank conflicts measured 0.
//
// Per tile t: 4 MFMA quadrants P1..P4, only 3 barriers (correctness-minimal):
//   entry: issue bf0,bf1 reads; stage A1/B1(t+1)->buf p^1; lgkmcnt(4); P1
//   issue af1 reads; lgkmcnt(8) [bf1 done, in-order LDS retire]; P2
//   BAR#1 (all B reads done block-wide); stage B0(t+2)->buf p; lgkmcnt(0); P3
//   BAR#2 (all A reads done); stage A0(t+2)->buf p; vmcnt(4) [tile t+1 landed,
//   newest 4 = t+2 staging still in flight]; BAR#3; preload af0(t+1); P4
// Counted lgkm waits let ds_reads overlap MFMA (the 37%-MfmaUtil stall in r1
// was read/MFMA lockstep); af0 preload hides the tile-entry read burst under P4.
template <int EPI>
__global__ __launch_bounds__(512, 2)
void gemm256_f16(const f16* __restrict__ A, int lda,
                 const f16* __restrict__ Bt, int ldb,
                 void* __restrict__ Cv, int ldc,
                 const float* __restrict__ bias, int K)
{
    __shared__ __align__(16) f16 sm[65536];   // 128 KiB
    f16* smf = sm;

    const int tid = threadIdx.x;
    const int l = tid & 63;

    // bijective XCD-chunk swizzle (m204), then column-major tile decompose
    const int gx = gridDim.x, gy = gridDim.y;
    int pid = blockIdx.y * gx + blockIdx.x;
    int nwg = gx * gy;
    int q = nwg >> 3, r8 = nwg & 7;
    int xcd = pid & 7, idx = pid >> 3;
    int swz = (xcd < r8) ? (xcd * (q + 1) + idx)
                         : (r8 * (q + 1) + (xcd - r8) * q + idx);
    const int by = swz % gy, bx = swz / gy;
    const int m0 = by * 256, n0 = bx * 256;

    const int wu = __builtin_amdgcn_readfirstlane(tid >> 6);  // wave 0..7
    const int wr = wu >> 2;        // M-half of block (2)
    const int wc = wu & 3;         // N-quarter of block (4)
    const int wst = wu * 512;      // per-wave LDS stage base (f16)

    // staging source: lane covers row (w*8 + l>>3) (+64*inst, +128*half),
    // col f16 = ((l&7)^(l>>3))*8  (inverse of read-side XOR swizzle)
    const int strow = wu * 8 + (l >> 3);
    const int stcol = ((l & 7) ^ (l >> 3)) * 8;
    const f16* Asrc = A + (size_t)(m0 + strow) * lda + stcol;
    const f16* Bsrc = Bt + (size_t)(n0 + strow) * ldb + stcol;

    // ds_read fragment addressing
    const int fr = l & 15;
    const int hi8 = (l >> 4) * 8;
    const int swl = (fr & 7) * 8;
    const int ca0 = hi8 ^ swl;            // K-slice 0, swizzled col (f16)
    const int ca1 = (32 + hi8) ^ swl;     // K-slice 1

    const int NT = K >> 6;

    f32x4 acc[8][4] = {};
    f16x8 af0[4][2], af1[4][2], bf0[2][2], bf1[2][2];

    // ---- prologue: stage tile0 (A0,A1,B0,B1) + B0(1),A0(1); preload af0(0) ----
    gl_lds16(Asrc, smf + wst);
    gl_lds16(Asrc + (size_t)64 * lda, smf + 4096 + wst);
    gl_lds16(Asrc + (size_t)128 * lda, smf + 8192 + wst);
    gl_lds16(Asrc + (size_t)192 * lda, smf + 8192 + 4096 + wst);
    gl_lds16(Bsrc, smf + 16384 + wst);
    gl_lds16(Bsrc + (size_t)64 * ldb, smf + 16384 + 4096 + wst);
    gl_lds16(Bsrc + (size_t)128 * ldb, smf + 16384 + 8192 + wst);
    gl_lds16(Bsrc + (size_t)192 * ldb, smf + 16384 + 8192 + 4096 + wst);
    if (NT > 1) {
        gl_lds16(Bsrc + 64, smf + 32768 + 16384 + wst);
        gl_lds16(Bsrc + 64 + (size_t)64 * ldb, smf + 32768 + 16384 + 4096 + wst);
        gl_lds16(Asrc + 64, smf + 32768 + wst);
        gl_lds16(Asrc + 64 + (size_t)64 * lda, smf + 32768 + 4096 + wst);
        asm volatile("s_waitcnt vmcnt(4)" ::: "memory");
    } else {
        asm volatile("s_waitcnt vmcnt(0)" ::: "memory");
    }
    S_BARRIER();
    {
        const f16* sAp0 = smf + wr * 8192 + fr * 64;
#pragma unroll
        for (int i = 0; i < 4; i++) {
            af0[i][0] = *(const f16x8*)(sAp0 + i * 1024 + ca0);
            af0[i][1] = *(const f16x8*)(sAp0 + i * 1024 + ca1);
        }
    }

#define MFMA_Q(MB, NB, AF, BF)                                                        \
    _Pragma("unroll") for (int i = 0; i < 4; i++)                                     \
    _Pragma("unroll") for (int j = 0; j < 2; j++) {                                   \
        acc[MB + i][NB + j] = __builtin_amdgcn_mfma_f32_16x16x32_f16(                 \
            AF[i][0], BF[j][0], acc[MB + i][NB + j], 0, 0, 0);                        \
        acc[MB + i][NB + j] = __builtin_amdgcn_mfma_f32_16x16x32_f16(                 \
            AF[i][1], BF[j][1], acc[MB + i][NB + j], 0, 0, 0);                        \
    }

    for (int t = 0; t < NT; ++t) {
        const int p = t & 1;
        const f16* sAp = smf + (p << 15) + wr * 8192 + fr * 64;
        const f16* sBp = smf + (p << 15) + 16384 + wc * 4096 + fr * 64;
        const bool s1 = (t + 1 < NT), s2 = (t + 2 < NT);

        // ---- entry: issue bf0,bf1 (8 ds_read); stage A1/B1(t+1) ----
#pragma unroll
        for (int j = 0; j < 2; j++) {
            bf0[j][0] = *(const f16x8*)(sBp + j * 1024 + ca0);
            bf0[j][1] = *(const f16x8*)(sBp + j * 1024 + ca1);
        }
#pragma unroll
        for (int j = 0; j < 2; j++) {
            bf1[j][0] = *(const f16x8*)(sBp + 2048 + j * 1024 + ca0);
            bf1[j][1] = *(const f16x8*)(sBp + 2048 + j * 1024 + ca1);
        }
        if (s1) {
            const f16* sa = Asrc + (size_t)128 * lda + (size_t)(t + 1) * 64;
            f16* da = smf + ((p ^ 1) << 15) + 8192 + wst;
            gl_lds16(sa, da);
            gl_lds16(sa + (size_t)64 * lda, da + 4096);
            const f16* sb = Bsrc + (size_t)128 * ldb + (size_t)(t + 1) * 64;
            f16* db = smf + ((p ^ 1) << 15) + 16384 + 8192 + wst;
            gl_lds16(sb, db);
            gl_lds16(sb + (size_t)64 * ldb, db + 4096);
        }
        asm volatile("s_waitcnt lgkmcnt(4)" ::: "memory");  // af0+bf0 done (bf1 out)
        SCHED_FENCE();
        __builtin_amdgcn_s_setprio(1);
        MFMA_Q(0, 0, af0, bf0);
        __builtin_amdgcn_s_setprio(0);

        // ---- issue af1 (8 ds_read); P2 needs bf1 only ----
#pragma unroll
        for (int i = 0; i < 4; i++) {
            af1[i][0] = *(const f16x8*)(sAp + 4096 + i * 1024 + ca0);
            af1[i][1] = *(const f16x8*)(sAp + 4096 + i * 1024 + ca1);
        }
        asm volatile("s_waitcnt lgkmcnt(8)" ::: "memory");  // bf1 done (af1 out)
        SCHED_FENCE();
        __builtin_amdgcn_s_setprio(1);
        MFMA_Q(0, 2, af0, bf1);
        __builtin_amdgcn_s_setprio(0);

        S_BARRIER();                                        // #1: all B reads done
        if (s2) {
            const f16* sb = Bsrc + (size_t)(t + 2) * 64;
            f16* db = smf + (p << 15) + 16384 + wst;
            gl_lds16(sb, db);
            gl_lds16(sb + (size_t)64 * ldb, db + 4096);
        }
        asm volatile("s_waitcnt lgkmcnt(0)" ::: "memory");  // af1 done
        SCHED_FENCE();
        __builtin_amdgcn_s_setprio(1);
        MFMA_Q(4, 2, af1, bf1);
        __builtin_amdgcn_s_setprio(0);

        S_BARRIER();                                        // #2: all A reads done
        if (s2) {
            const f16* sa = Asrc + (size_t)(t + 2) * 64;
            f16* da = smf + (p << 15) + wst;
            gl_lds16(sa, da);
            gl_lds16(sa + (size_t)64 * lda, da + 4096);
            asm volatile("s_waitcnt vmcnt(4)" ::: "memory");
        } else if (s1) {
            asm volatile("s_waitcnt vmcnt(0)" ::: "memory");
        }
        if (s1) {
            S_BARRIER();                                    // #3: tile t+1 visible
            const f16* sApN = smf + ((p ^ 1) << 15) + wr * 8192 + fr * 64;
#pragma unroll
            for (int i = 0; i < 4; i++) {
                af0[i][0] = *(const f16x8*)(sApN + i * 1024 + ca0);
                af0[i][1] = *(const f16x8*)(sApN + i * 1024 + ca1);
            }
        }
        __builtin_amdgcn_s_setprio(1);
        MFMA_Q(4, 0, af1, bf0);                             // P4 overlaps af0 preload
        __builtin_amdgcn_s_setprio(0);
    }
#undef MFMA_Q

    // ---- epilogue: C/D layout col=lane&15, row=(lane>>4)*4+reg ----
    const int q4 = (l >> 4) * 4;
    float bc[4];
#pragma unroll
    for (int nt = 0; nt < 4; nt++) {
        if constexpr (EPI == EPI_F16_BIASCOL || EPI == EPI_F32_BIASCOL)
            bc[nt] = bias[n0 + wc * 64 + nt * 16 + fr];
        else
            bc[nt] = 0.f;
    }
#pragma unroll
    for (int mt = 0; mt < 8; mt++)
#pragma unroll
        for (int r = 0; r < 4; r++) {
            int row = m0 + wr * 128 + mt * 16 + q4 + r;
            float rowv = 0.f;
            if constexpr (EPI == EPI_F16_BIASROW) rowv = bias[row];
            if constexpr (EPI == EPI_F16_DIVROW) rowv = 1.f / bias[row];
#pragma unroll
            for (int nt = 0; nt < 4; nt++) {
                int col = n0 + wc * 64 + nt * 16 + fr;
                float v = acc[mt][nt][r];
                if constexpr (EPI == EPI_F16_BIASROW) {
                    ((f16*)Cv)[(size_t)row * ldc + col] = (f16)(v + rowv);
                } else if constexpr (EPI == EPI_F16_DIVROW) {
                    ((f16*)Cv)[(size_t)row * ldc + col] = (f16)(v * rowv);
                } else if constexpr (EPI == EPI_F16_BIASCOL) {
                    ((f16*)Cv)[(size_t)row * ldc + col] = (f16)(v + bc[nt]);
                } else {
                    ((float*)Cv)[(size_t)row * ldc + col] = v + bc[nt];
                }
            }
        }
}

// ---------------------------------------------------------------------------
// row sums of exp-scores: lsum[z][n] = sum_m P[z][n][m]. grid (N, HB), block 256.
__global__ void k_rowsum(const f16* __restrict__ P, float* __restrict__ lsum,
                         long hstride)
{
    const f16x8* p8 = (const f16x8*)(P + (long)blockIdx.y * hstride + (long)blockIdx.x * 4096);
    int t = threadIdx.x, w = t >> 6, l = t & 63;
    f16x8 a = p8[t], b = p8[256 + t];
    float s = 0.f;
#pragma unroll
    for (int j = 0; j < 8; j++) s += (float)a[j] + (float)b[j];
#pragma unroll
    for (int o = 32; o; o >>= 1) s += __shfl_xor(s, o);
    __shared__ float red[4];
    if (l == 0) red[w] = s;
    __syncthreads();
    if (t == 0)
        lsum[(long)blockIdx.y * gridDim.x + blockIdx.x] = red[0] + red[1] + red[2] + red[3];
}

// ---------------------------------------------------------------------------
// LayerNorm over 3584 cols of (ctx + resid), both f16, -> f16 out. grid N, block 256.
__global__ void k_layernorm(const f16* __restrict__ ctxp, const f16* __restrict__ resp,
                            const float* __restrict__ g, const float* __restrict__ be,
                            f16* __restrict__ out)
{
    long base = (long)blockIdx.x * LLM_DIM;
    const f16x8* c8 = (const f16x8*)(ctxp + base);
    const f16x8* r8 = (const f16x8*)(resp + base);
    int t = threadIdx.x, w = t >> 6, l = t & 63;
    bool has2 = t < 192;
    f16x8 a0 = c8[t], b0 = r8[t];
    f16x8 a1 = {}, b1 = {};
    if (has2) { a1 = c8[256 + t]; b1 = r8[256 + t]; }
    float v[16];
    float s = 0.f;
#pragma unroll
    for (int j = 0; j < 8; j++) { v[j] = (float)a0[j] + (float)b0[j]; s += v[j]; }
#pragma unroll
    for (int j = 0; j < 8; j++) v[8 + j] = (float)a1[j] + (float)b1[j];
    if (has2)
#pragma unroll
        for (int j = 0; j < 8; j++) s += v[8 + j];
#pragma unroll
    for (int o = 32; o; o >>= 1) s += __shfl_xor(s, o);
    __shared__ float r1[4];
    if (l == 0) r1[w] = s;
    __syncthreads();
    float mu = (r1[0] + r1[1] + r1[2] + r1[3]) * (1.f / LLM_DIM);
    float s2 = 0.f;
#pragma unroll
    for (int j = 0; j < 8; j++) { float d = v[j] - mu; s2 += d * d; }
    if (has2)
#pragma unroll
        for (int j = 8; j < 16; j++) { float d = v[j] - mu; s2 += d * d; }
#pragma unroll
    for (int o = 32; o; o >>= 1) s2 += __shfl_xor(s2, o);
    __shared__ float r2[4];
    if (l == 0) r2[w] = s2;
    __syncthreads();
    float var = (r2[0] + r2[1] + r2[2] + r2[3]) * (1.f / LLM_DIM);
    float inv = rsqrtf(var + LN_EPS);
    f16* op = out + base;
    f16x8 o0, o1;
#pragma unroll
    for (int j = 0; j < 8; j++) {
        int c = t * 8 + j;
        o0[j] = (f16)((v[j] - mu) * inv * g[c] + be[c]);
    }
    ((f16x8*)op)[t] = o0;
    if (has2) {
#pragma unroll
        for (int j = 0; j < 8; j++) {
            int c = (256 + t) * 8 + j;
            o1[j] = (f16)((v[8 + j] - mu) * inv * g[c] + be[c]);
        }
        ((f16x8*)op)[256 + t] = o1;
    }
}

// ---------------------------------------------------------------------------
extern "C" void kernel_launch(void* const* d_in, const int* in_sizes, int n_in,
                              void* d_out, int out_size, void* d_ws, size_t ws_size,
                              hipStream_t stream)
{
    const float* target  = (const float*)d_in[0];
    const float* source  = (const float*)d_in[1];
    const float* value   = (const float*)d_in[2];
    const float* wq_w    = (const float*)d_in[3];
    const float* wq_b    = (const float*)d_in[4];
    const float* wk_w    = (const float*)d_in[5];
    const float* wk_b    = (const float*)d_in[6];
    const float* wv_w    = (const float*)d_in[7];
    const float* wv_b    = (const float*)d_in[8];
    const float* resid_w = (const float*)d_in[9];
    const float* resid_b = (const float*)d_in[10];
    const float* out_w   = (const float*)d_in[11];
    const float* out_b   = (const float*)d_in[12];
    const float* ln_g    = (const float*)d_in[13];
    const float* ln_b    = (const float*)d_in[14];

    const int N = in_sizes[0] / REGION_DIM;  // 4096
    const int M = in_sizes[1] / LLM_DIM;     // 4096

    // ---- workspace: persistent ~149.9 MB + one 67.1 MB aliased union = 217 MB
    char* ws = (char*)d_ws;
    size_t off = 0;
    auto alloc = [&](size_t bytes) { void* p = ws + off; off += (bytes + 255) & ~(size_t)255; return p; };
    f16*   tgt16   = (f16*)alloc((size_t)N * KPAD_REGION * 2);
    f16*   residT  = (f16*)alloc((size_t)LLM_DIM * KPAD_REGION * 2); // [3584][160]
    f16*   outT    = (f16*)alloc((size_t)LLM_DIM * LLM_DIM * 2);     // [3584][3584]
    f16*   wqT     = (f16*)alloc((size_t)QK_COLS * KPAD_REGION * 2); // [256][160]
    float* biasK   = (float*)alloc(QK_COLS * 4);
    float* biasQ   = (float*)alloc(QK_COLS * 4);
    f16*   Qtmp    = (f16*)alloc((size_t)N * QK_COLS * 2);           // [N][256]
    f16*   Ktmp    = (f16*)alloc((size_t)M * QK_COLS * 2);           // [M][256]
    f16*   Vt      = (f16*)alloc((size_t)LLM_DIM * M * 2);           // [H*896][M]
    f16*   residbf = (f16*)alloc((size_t)N * LLM_DIM * 2);           // resid proj, f16
    f16*   ctx     = (f16*)alloc((size_t)N * LLM_DIM * 2);           // attn output, f16
    f16*   xln     = (f16*)alloc((size_t)N * LLM_DIM * 2);
    float* lsum    = (float*)alloc((size_t)2 * N * 4);               // [HB][N]
    const int HB = 2;
    char* U = (char*)alloc((size_t)HB * N * M * 2);                  // 67.1 MB
    f16* val16 = (f16*)U;
    f16* wvT   = (f16*)(U + (size_t)M * LLM_DIM * 2);
    f16* src16 = (f16*)U;
    f16* wkT   = (f16*)(U + (size_t)M * LLM_DIM * 2);
    f16* attnB = (f16*)U;
    (void)n_in; (void)out_size; (void)ws_size;

    dim3 tb(32, 8);

    // ---- phase 0: target-side prep ----
    k_convert_pad<<<dim3(1, N), 256, 0, stream>>>(target, tgt16, REGION_DIM, KPAD_REGION);
    k_transpose<<<dim3(LLM_DIM / 32, KPAD_REGION / 32, 1), tb, 0, stream>>>(
        resid_w, residT, REGION_DIM, LLM_DIM, KPAD_REGION, LLM_DIM, 0, 0);
    k_transpose<<<dim3(LLM_DIM / 32, LLM_DIM / 32, 1), tb, 0, stream>>>(
        out_w, outT, LLM_DIM, LLM_DIM, LLM_DIM, LLM_DIM, 0, 0);
    k_headpad_w<<<dim3(1, QK_COLS), 256, 0, stream>>>(wq_w, wq_b, wqT, biasQ, REGION_DIM, KPAD_REGION);

    gemm_f16<EPI_F16_BIASCOL><<<dim3(QK_COLS / 128, N / 128), 256, 0, stream>>>(
        tgt16, KPAD_REGION, 0, wqT, KPAD_REGION, 0, Qtmp, QK_COLS, 0, biasQ, 0, 1.f, KPAD_REGION);
    gemm_f16<EPI_F16_BIASCOL><<<dim3(LLM_DIM / 128, N / 128), 256, 0, stream>>>(
        tgt16, KPAD_REGION, 0, residT, KPAD_REGION, 0, residbf, LLM_DIM, 0, resid_b, 0, 1.f, KPAD_REGION);

    // ---- phase V: value projection (256^2 decoupled GEMM) ----
    k_convert_pad<<<dim3(LLM_DIM / 256, M), 256, 0, stream>>>(value, val16, LLM_DIM, LLM_DIM);
    k_transpose<<<dim3(V_HEAD / 32, LLM_DIM / 32, NUM_HEADS), tb, 0, stream>>>(
        wv_w, wvT, LLM_DIM, V_HEAD, LLM_DIM, V_HEAD, (long)LLM_DIM * V_HEAD, (long)V_HEAD * LLM_DIM);
    gemm256_f16<EPI_F16_BIASROW><<<dim3(M / 256, LLM_DIM / 256), 512, 0, stream>>>(
        wvT, LLM_DIM, val16, LLM_DIM, Vt, M, wv_b, LLM_DIM);

    // ---- phase K: key projection ----
    k_convert_pad<<<dim3(LLM_DIM / 256, M), 256, 0, stream>>>(source, src16, LLM_DIM, LLM_DIM);
    k_headpad_w<<<dim3(LLM_DIM / 256, QK_COLS), 256, 0, stream>>>(wk_w, wk_b, wkT, biasK, LLM_DIM, LLM_DIM);
    gemm_f16<EPI_F16_BIASCOL><<<dim3(QK_COLS / 128, M / 128), 256, 0, stream>>>(
        src16, LLM_DIM, 0, wkT, LLM_DIM, 0, Ktmp, QK_COLS, 0, biasK, 0, 1.f, LLM_DIM);

    // ---- phase A: attention, 2 heads at a time ----
    const float sc = 0.16666667f;  // 1/sqrt(36)
    for (int h0 = 0; h0 < NUM_HEADS; h0 += HB) {
        gemm_f16<EPI_F16_EXPSCALE><<<dim3(M / 128, N / 128, HB), 256, 0, stream>>>(
            Qtmp + h0 * HEAD_PAD, QK_COLS, HEAD_PAD,
            Ktmp + h0 * HEAD_PAD, QK_COLS, HEAD_PAD,
            attnB, M, (long)N * M, nullptr, 0, sc, HEAD_PAD);
        k_rowsum<<<dim3(N, HB), 256, 0, stream>>>(attnB, lsum, (long)N * M);
        gemm_f16<EPI_F16_DIVROW><<<dim3(V_HEAD / 128, N / 128, HB), 256, 0, stream>>>(
            attnB, M, (long)N * M,
            Vt + (size_t)h0 * V_HEAD * M, M, (long)V_HEAD * M,
            ctx + (size_t)h0 * V_HEAD, LLM_DIM, V_HEAD, lsum, N, 1.f, M);
    }

    // ---- epilogue: LayerNorm + output projection (256^2 decoupled GEMM) ----
    k_layernorm<<<N, 256, 0, stream>>>(ctx, residbf, ln_g, ln_b, xln);
    gemm256_f16<EPI_F32_BIASCOL><<<dim3(LLM_DIM / 256, N / 256), 512, 0, stream>>>(
        xln, LLM_DIM, outT, LLM_DIM, (float*)d_out, LLM_DIM, out_b, LLM_DIM);
}

// Round 3
// 803.982 us; speedup vs baseline: 1.1591x; 1.0516x over previous
//
#include <hip/hip_runtime.h>

typedef _Float16 f16;
typedef _Float16 f16x8 __attribute__((ext_vector_type(8)));
typedef float f32x4 __attribute__((ext_vector_type(4)));

#define REGION_DIM 144
#define LLM_DIM 3584
#define NUM_HEADS 4
#define HEAD_DIM 36
#define HEAD_PAD 64      // head_dim padded to 64 -> 4 heads = 256 cols
#define QK_COLS 256      // NUM_HEADS * HEAD_PAD
#define KPAD_REGION 160  // region_dim padded to multiple of 32
#define V_HEAD 896
#define LN_EPS 1e-5f

// ---------------------------------------------------------------------------
// async global->LDS, 16B per lane (m97 pattern)
__device__ __forceinline__ void gl_lds16(const f16* g, f16* l)
{
    __builtin_amdgcn_global_load_lds(
        (const __attribute__((address_space(1))) unsigned int*)g,
        (__attribute__((address_space(3))) unsigned int*)l, 16, 0, 0);
}

#define S_BARRIER() do { asm volatile("" ::: "memory"); __builtin_amdgcn_s_barrier(); asm volatile("" ::: "memory"); } while (0)
#define SCHED_FENCE() __builtin_amdgcn_sched_barrier(0)

// ---------------------------------------------------------------------------
// fp32 -> fp16 convert with optional column zero-pad. grid: (ceil(Cout/256), R)
__global__ void k_convert_pad(const float* __restrict__ in, f16* __restrict__ out,
                              int Cin, int Cout)
{
    int r = blockIdx.y;
    int c = blockIdx.x * 256 + threadIdx.x;
    if (c >= Cout) return;
    float v = (c < Cin) ? in[(long)r * Cin + c] : 0.f;
    out[(long)r * Cout + c] = (f16)v;
}

// ---------------------------------------------------------------------------
// transpose+convert: out[b][c][r] = (r<R && c<C ? in[b][r][c] : 0), out [Cpad][Rpad]
// block (32,8), grid (Cpad/32, ceil(Rpad/32), batch)
__global__ void k_transpose(const float* __restrict__ in, f16* __restrict__ out,
                            int R, int C, int Rpad, int Cpad,
                            long in_bstride, long out_bstride)
{
    __shared__ float tile[32][33];
    const float* ip = in + (long)blockIdx.z * in_bstride;
    f16* op = out + (long)blockIdx.z * out_bstride;
    int r0 = blockIdx.y * 32, c0 = blockIdx.x * 32;
    int tx = threadIdx.x, ty = threadIdx.y;
#pragma unroll
    for (int i = 0; i < 32; i += 8) {
        int r = r0 + ty + i, c = c0 + tx;
        tile[ty + i][tx] = (r < R && c < C) ? ip[(long)r * C + c] : 0.f;
    }
    __syncthreads();
#pragma unroll
    for (int i = 0; i < 32; i += 8) {
        int c = c0 + ty + i, r = r0 + tx;
        if (c < Cpad && r < Rpad) op[(long)c * Rpad + r] = (f16)tile[tx][ty + i];
    }
}

// ---------------------------------------------------------------------------
// Build head-padded transposed QK weight: outW[h*64+kk][e] = (kk<36 && e<E) ? w[e][h*36+kk] : 0
// also padded bias. grid (ceil(Epad/256), 256)
__global__ void k_headpad_w(const float* __restrict__ w, const float* __restrict__ b,
                            f16* __restrict__ outW, float* __restrict__ outB,
                            int E, int Epad)
{
    int hp = blockIdx.y;
    int h = hp >> 6, kk = hp & 63;
    int d = h * HEAD_DIM + kk;
    bool valid = (kk < HEAD_DIM);
    int e = blockIdx.x * 256 + threadIdx.x;
    if (e < Epad) {
        float v = (valid && e < E) ? w[(long)e * REGION_DIM + d] : 0.f;
        outW[(long)hp * Epad + e] = (f16)v;
    }
    if (blockIdx.x == 0 && threadIdx.x == 0) outB[hp] = valid ? b[d] : 0.f;
}

// ---------------------------------------------------------------------------
enum { EPI_F16_EXPSCALE = 0,  // store exp(v*scale)   (softmax numerator, no max-sub)
       EPI_F16_BIASROW  = 1,  // store v + bias[row]
       EPI_F16_DIVROW   = 2,  // store v / bias[row]  (softmax denominator)
       EPI_F32_BIASCOL  = 3,  // store fp32 v + bias[col]
       EPI_F16_BIASCOL  = 4,
       EPI_F16_EXPSUM   = 5 };// exp(v*scale) + per-block row-partial sums -> rowpart

// ---------------------------------------------------------------------------
// Templated MFMA GEMM (128x128 tile, 4 waves) — small/odd-shaped GEMMs + QK^T.
template <int EPI>
__global__ __launch_bounds__(256, 2)
void gemm_f16(const f16* __restrict__ A, int lda, long sAz,
              const f16* __restrict__ Bt, int ldb, long sBz,
              void* __restrict__ Cv, int ldc, long sCz,
              const float* __restrict__ bias, long sbz, float scale, int K,
              float* __restrict__ rowpart)
{
    __shared__ __align__(16) f16 sA[128 * 32];
    __shared__ __align__(16) f16 sB[128 * 32];
    __shared__ float ps[256];   // EPI_F16_EXPSUM row-partial combine (1 KB)
    const int tid = threadIdx.x;
    const int z = blockIdx.z;
    A += (long)z * sAz;
    Bt += (long)z * sBz;
    if (bias) bias += (long)z * sbz;

    const int gx = gridDim.x, gy = gridDim.y;
    int pid = blockIdx.y * gx + blockIdx.x;
    const int GROUP = 8;
    int span = GROUP * gx;
    int gid = pid / span;
    int y0 = gid * GROUP;
    int gsz = (gy - y0 < GROUP) ? (gy - y0) : GROUP;
    int rem = pid - gid * span;
    const int by = y0 + rem % gsz;
    const int bx = rem / gsz;
    const int m0 = by * 128, n0 = bx * 128;

    const int w = tid >> 6, l = tid & 63;
    const int wu = __builtin_amdgcn_readfirstlane(w);
    const int wr = w >> 1, wc = w & 1;

    f32x4 acc[4][4] = {};

    const int srow = tid >> 2;
    const int scol = (tid & 3) * 8;
    const f16* Ag = A + (long)(m0 + srow) * lda + scol;
    const f16* Bg = Bt + (long)(n0 + srow) * ldb + scol;
    f16* sA0 = sA + wu * 512;
    f16* sA1 = sA + 2048 + wu * 512;
    f16* sB0 = sB + wu * 512;
    f16* sB1 = sB + 2048 + wu * 512;
    const int qk = (l >> 4) * 8;
    const int fr = l & 15;

    for (int k0 = 0; k0 < K; k0 += 32) {
        __syncthreads();
        gl_lds16(Ag + k0, sA0);
        gl_lds16(Ag + (long)64 * lda + k0, sA1);
        gl_lds16(Bg + k0, sB0);
        gl_lds16(Bg + (long)64 * ldb + k0, sB1);
        __syncthreads();

        f16x8 af[4], bf[4];
#pragma unroll
        for (int mt = 0; mt < 4; mt++)
            af[mt] = *(const f16x8*)&sA[(wr * 64 + mt * 16 + fr) * 32 + qk];
#pragma unroll
        for (int nt = 0; nt < 4; nt++)
            bf[nt] = *(const f16x8*)&sB[(wc * 64 + nt * 16 + fr) * 32 + qk];
#pragma unroll
        for (int mt = 0; mt < 4; mt++)
#pragma unroll
            for (int nt = 0; nt < 4; nt++)
                acc[mt][nt] = __builtin_amdgcn_mfma_f32_16x16x32_f16(af[mt], bf[nt], acc[mt][nt], 0, 0, 0);
    }

    const int q4 = (l >> 4) * 4;
    float bc[4];
#pragma unroll
    for (int nt = 0; nt < 4; nt++) {
        if constexpr (EPI == EPI_F16_BIASCOL || EPI == EPI_F32_BIASCOL)
            bc[nt] = bias[n0 + wc * 64 + nt * 16 + fr];
        else
            bc[nt] = 0.f;
    }
    float rsum[4][4];
    if constexpr (EPI == EPI_F16_EXPSUM) {
#pragma unroll
        for (int a = 0; a < 4; a++)
#pragma unroll
            for (int b = 0; b < 4; b++) rsum[a][b] = 0.f;
    }
#pragma unroll
    for (int mt = 0; mt < 4; mt++)
#pragma unroll
        for (int r = 0; r < 4; r++) {
            int row = m0 + wr * 64 + mt * 16 + q4 + r;
            float rowv = 0.f;
            if constexpr (EPI == EPI_F16_BIASROW) rowv = bias[row];
            if constexpr (EPI == EPI_F16_DIVROW) rowv = 1.f / bias[row];
#pragma unroll
            for (int nt = 0; nt < 4; nt++) {
                int col = n0 + wc * 64 + nt * 16 + fr;
                float v = acc[mt][nt][r];
                if constexpr (EPI == EPI_F16_EXPSCALE || EPI == EPI_F16_EXPSUM) {
                    float e = __expf(v * scale);
                    ((f16*)Cv + (long)z * sCz)[(long)row * ldc + col] = (f16)e;
                    if constexpr (EPI == EPI_F16_EXPSUM) rsum[mt][r] += e;
                } else if constexpr (EPI == EPI_F16_BIASROW) {
                    ((f16*)Cv + (long)z * sCz)[(long)row * ldc + col] = (f16)(v + rowv);
                } else if constexpr (EPI == EPI_F16_DIVROW) {
                    ((f16*)Cv + (long)z * sCz)[(long)row * ldc + col] = (f16)(v * rowv);
                } else if constexpr (EPI == EPI_F16_BIASCOL) {
                    ((f16*)Cv + (long)z * sCz)[(long)row * ldc + col] = (f16)(v + bc[nt]);
                } else {
                    ((float*)Cv + (long)z * sCz)[(long)row * ldc + col] = v + bc[nt];
                }
            }
        }

    if constexpr (EPI == EPI_F16_EXPSUM) {
        // deterministic per-block 128-row partial sums of exp-scores.
        // lanes sharing (l>>4) hold the same rows; xor-reduce over fr bits.
#pragma unroll
        for (int mt = 0; mt < 4; mt++)
#pragma unroll
            for (int r = 0; r < 4; r++) {
                float s = rsum[mt][r];
                s += __shfl_xor(s, 1);
                s += __shfl_xor(s, 2);
                s += __shfl_xor(s, 4);
                s += __shfl_xor(s, 8);
                if (fr == 0) ps[wc * 128 + wr * 64 + mt * 16 + q4 + r] = s;
            }
        __syncthreads();
        if (tid < 128) {
            long rows = (long)gy * 128;
            rowpart[((long)z * gx + bx) * rows + m0 + tid] = ps[tid] + ps[128 + tid];
        }
    }
}

// ---------------------------------------------------------------------------
// 256x256 / BK=64 / 8-wave GEMM, decoupled-phase schedule (r2) — proven 1047 TF.
template <int EPI>
__global__ __launch_bounds__(512, 2)
void gemm256_f16(const f16* __restrict__ A, int lda,
                 const f16* __restrict__ Bt, int ldb,
                 void* __restrict__ Cv, int ldc,
                 const float* __restrict__ bias, int K)
{
    __shared__ __align__(16) f16 sm[65536];   // 128 KiB
    f16* smf = sm;

    const int tid = threadIdx.x;
    const int l = tid & 63;

    const int gx = gridDim.x, gy = gridDim.y;
    int pid = blockIdx.y * gx + blockIdx.x;
    int nwg = gx * gy;
    int q = nwg >> 3, r8 = nwg & 7;
    int xcd = pid & 7, idx = pid >> 3;
    int swz = (xcd < r8) ? (xcd * (q + 1) + idx)
                         : (r8 * (q + 1) + (xcd - r8) * q + idx);
    const int by = swz % gy, bx = swz / gy;
    const int m0 = by * 256, n0 = bx * 256;

    const int wu = __builtin_amdgcn_readfirstlane(tid >> 6);  // wave 0..7
    const int wr = wu >> 2;        // M-half of block (2)
    const int wc = wu & 3;         // N-quarter of block (4)
    const int wst = wu * 512;      // per-wave LDS stage base (f16)

    const int strow = wu * 8 + (l >> 3);
    const int stcol = ((l & 7) ^ (l >> 3)) * 8;
    const f16* Asrc = A + (size_t)(m0 + strow) * lda + stcol;
    const f16* Bsrc = Bt + (size_t)(n0 + strow) * ldb + stcol;

    const int fr = l & 15;
    const int hi8 = (l >> 4) * 8;
    const int swl = (fr & 7) * 8;
    const int ca0 = hi8 ^ swl;
    const int ca1 = (32 + hi8) ^ swl;

    const int NT = K >> 6;

    f32x4 acc[8][4] = {};
    f16x8 af0[4][2], af1[4][2], bf0[2][2], bf1[2][2];

    gl_lds16(Asrc, smf + wst);
    gl_lds16(Asrc + (size_t)64 * lda, smf + 4096 + wst);
    gl_lds16(Asrc + (size_t)128 * lda, smf + 8192 + wst);
    gl_lds16(Asrc + (size_t)192 * lda, smf + 8192 + 4096 + wst);
    gl_lds16(Bsrc, smf + 16384 + wst);
    gl_lds16(Bsrc + (size_t)64 * ldb, smf + 16384 + 4096 + wst);
    gl_lds16(Bsrc + (size_t)128 * ldb, smf + 16384 + 8192 + wst);
    gl_lds16(Bsrc + (size_t)192 * ldb, smf + 16384 + 8192 + 4096 + wst);
    if (NT > 1) {
        gl_lds16(Bsrc + 64, smf + 32768 + 16384 + wst);
        gl_lds16(Bsrc + 64 + (size_t)64 * ldb, smf + 32768 + 16384 + 4096 + wst);
        gl_lds16(Asrc + 64, smf + 32768 + wst);
        gl_lds16(Asrc + 64 + (size_t)64 * lda, smf + 32768 + 4096 + wst);
        asm volatile("s_waitcnt vmcnt(4)" ::: "memory");
    } else {
        asm volatile("s_waitcnt vmcnt(0)" ::: "memory");
    }
    S_BARRIER();
    {
        const f16* sAp0 = smf + wr * 8192 + fr * 64;
#pragma unroll
        for (int i = 0; i < 4; i++) {
            af0[i][0] = *(const f16x8*)(sAp0 + i * 1024 + ca0);
            af0[i][1] = *(const f16x8*)(sAp0 + i * 1024 + ca1);
        }
    }

#define MFMA_Q(MB, NB, AF, BF)                                                        \
    _Pragma("unroll") for (int i = 0; i < 4; i++)                                     \
    _Pragma("unroll") for (int j = 0; j < 2; j++) {                                   \
        acc[MB + i][NB + j] = __builtin_amdgcn_mfma_f32_16x16x32_f16(                 \
            AF[i][0], BF[j][0], acc[MB + i][NB + j], 0, 0, 0);                        \
        acc[MB + i][NB + j] = __builtin_amdgcn_mfma_f32_16x16x32_f16(                 \
            AF[i][1], BF[j][1], acc[MB + i][NB + j], 0, 0, 0);                        \
    }

    for (int t = 0; t < NT; ++t) {
        const int p = t & 1;
        const f16* sAp = smf + (p << 15) + wr * 8192 + fr * 64;
        const f16* sBp = smf + (p << 15) + 16384 + wc * 4096 + fr * 64;
        const bool s1 = (t + 1 < NT), s2 = (t + 2 < NT);

#pragma unroll
        for (int j = 0; j < 2; j++) {
            bf0[j][0] = *(const f16x8*)(sBp + j * 1024 + ca0);
            bf0[j][1] = *(const f16x8*)(sBp + j * 1024 + ca1);
        }
#pragma unroll
        for (int j = 0; j < 2; j++) {
            bf1[j][0] = *(const f16x8*)(sBp + 2048 + j * 1024 + ca0);
            bf1[j][1] = *(const f16x8*)(sBp + 2048 + j * 1024 + ca1);
        }
        if (s1) {
            const f16* sa = Asrc + (size_t)128 * lda + (size_t)(t + 1) * 64;
            f16* da = smf + ((p ^ 1) << 15) + 8192 + wst;
            gl_lds16(sa, da);
            gl_lds16(sa + (size_t)64 * lda, da + 4096);
            const f16* sb = Bsrc + (size_t)128 * ldb + (size_t)(t + 1) * 64;
            f16* db = smf + ((p ^ 1) << 15) + 16384 + 8192 + wst;
            gl_lds16(sb, db);
            gl_lds16(sb + (size_t)64 * ldb, db + 4096);
        }
        asm volatile("s_waitcnt lgkmcnt(4)" ::: "memory");
        SCHED_FENCE();
        __builtin_amdgcn_s_setprio(1);
        MFMA_Q(0, 0, af0, bf0);
        __builtin_amdgcn_s_setprio(0);

#pragma unroll
        for (int i = 0; i < 4; i++) {
            af1[i][0] = *(const f16x8*)(sAp + 4096 + i * 1024 + ca0);
            af1[i][1] = *(const f16x8*)(sAp + 4096 + i * 1024 + ca1);
        }
        asm volatile("s_waitcnt lgkmcnt(8)" ::: "memory");
        SCHED_FENCE();
        __builtin_amdgcn_s_setprio(1);
        MFMA_Q(0, 2, af0, bf1);
        __builtin_amdgcn_s_setprio(0);

        S_BARRIER();
        if (s2) {
            const f16* sb = Bsrc + (size_t)(t + 2) * 64;
            f16* db = smf + (p << 15) + 16384 + wst;
            gl_lds16(sb, db);
            gl_lds16(sb + (size_t)64 * ldb, db + 4096);
        }
        asm volatile("s_waitcnt lgkmcnt(0)" ::: "memory");
        SCHED_FENCE();
        __builtin_amdgcn_s_setprio(1);
        MFMA_Q(4, 2, af1, bf1);
        __builtin_amdgcn_s_setprio(0);

        S_BARRIER();
        if (s2) {
            const f16* sa = Asrc + (size_t)(t + 2) * 64;
            f16* da = smf + (p << 15) + wst;
            gl_lds16(sa, da);
            gl_lds16(sa + (size_t)64 * lda, da + 4096);
            asm volatile("s_waitcnt vmcnt(4)" ::: "memory");
        } else if (s1) {
            asm volatile("s_waitcnt vmcnt(0)" ::: "memory");
        }
        if (s1) {
            S_BARRIER();
            const f16* sApN = smf + ((p ^ 1) << 15) + wr * 8192 + fr * 64;
#pragma unroll
            for (int i = 0; i < 4; i++) {
                af0[i][0] = *(const f16x8*)(sApN + i * 1024 + ca0);
                af0[i][1] = *(const f16x8*)(sApN + i * 1024 + ca1);
            }
        }
        __builtin_amdgcn_s_setprio(1);
        MFMA_Q(4, 0, af1, bf0);
        __builtin_amdgcn_s_setprio(0);
    }
#undef MFMA_Q

    const int q4 = (l >> 4) * 4;
    float bc[4];
#pragma unroll
    for (int nt = 0; nt < 4; nt++) {
        if constexpr (EPI == EPI_F16_BIASCOL || EPI == EPI_F32_BIASCOL)
            bc[nt] = bias[n0 + wc * 64 + nt * 16 + fr];
        else
            bc[nt] = 0.f;
    }
#pragma unroll
    for (int mt = 0; mt < 8; mt++)
#pragma unroll
        for (int r = 0; r < 4; r++) {
            int row = m0 + wr * 128 + mt * 16 + q4 + r;
            float rowv = 0.f;
            if constexpr (EPI == EPI_F16_BIASROW) rowv = bias[row];
            if constexpr (EPI == EPI_F16_DIVROW) rowv = 1.f / bias[row];
#pragma unroll
            for (int nt = 0; nt < 4; nt++) {
                int col = n0 + wc * 64 + nt * 16 + fr;
                float v = acc[mt][nt][r];
                if constexpr (EPI == EPI_F16_BIASROW) {
                    ((f16*)Cv)[(size_t)row * ldc + col] = (f16)(v + rowv);
                } else if constexpr (EPI == EPI_F16_DIVROW) {
                    ((f16*)Cv)[(size_t)row * ldc + col] = (f16)(v * rowv);
                } else if constexpr (EPI == EPI_F16_BIASCOL) {
                    ((f16*)Cv)[(size_t)row * ldc + col] = (f16)(v + bc[nt]);
                } else {
                    ((float*)Cv)[(size_t)row * ldc + col] = v + bc[nt];
                }
            }
        }
}

// ---------------------------------------------------------------------------
// PV GEMM: 256x128 / BK=64 / 8-wave / z-batched, decoupled schedule.
// C[z][M rows][128*gx cols at ldc] = A[z][M][K] * Bt[z][128*gx][K]^T, / lsum[row].
// 896 = 7*128 -> grid (7, M/256, HB) = 224 blocks, full chip. NT = K/64 >= 2.
// LDS 96 KiB: buf p at p*24576 f16; A 256x64 at +0 (halves of 128 rows at
// +0/+8192), B 128x64 at +16384. All frag reads at tile entry -> whole buf
// dead after BAR#1 -> stage t+2 there; vmcnt(6) = t+1 landed, t+2 in flight.
__global__ __launch_bounds__(512, 2)
void gemm_pv(const f16* __restrict__ A, int lda, long sAz,
             const f16* __restrict__ Bt, int ldb, long sBz,
             f16* __restrict__ C, int ldc, long sCz,
             const float* __restrict__ lsum, long slz, int K)
{
    __shared__ __align__(16) f16 sm[49152];   // 96 KiB
    const int tid = threadIdx.x;
    const int l = tid & 63;
    const int z = blockIdx.z;
    A += (size_t)z * sAz;
    Bt += (size_t)z * sBz;
    C += (size_t)z * sCz;
    lsum += (size_t)z * slz;

    const int gx = gridDim.x, gy = gridDim.y;
    int pid = blockIdx.y * gx + blockIdx.x;
    int nwg = gx * gy;
    int q = nwg >> 3, r8 = nwg & 7;
    int xcd = pid & 7, idx = pid >> 3;
    int swz = (xcd < r8) ? (xcd * (q + 1) + idx)
                         : (r8 * (q + 1) + (xcd - r8) * q + idx);
    const int by = swz % gy, bx = swz / gy;
    const int m0 = by * 256, n0 = bx * 128;

    const int wu = __builtin_amdgcn_readfirstlane(tid >> 6);  // 0..7
    const int wr = wu >> 1;     // 0..3: 64-row slice
    const int wc = wu & 1;      // 0..1: 64-col slice
    const int wst = wu * 512;

    const int strow = wu * 8 + (l >> 3);
    const int stcol = ((l & 7) ^ (l >> 3)) * 8;
    const f16* Asrc = A + (size_t)(m0 + strow) * lda + stcol;
    const f16* Bsrc = Bt + (size_t)(n0 + strow) * ldb + stcol;

    const int fr = l & 15;
    const int hi8 = (l >> 4) * 8;
    const int swl = (fr & 7) * 8;
    const int ca0 = hi8 ^ swl;
    const int ca1 = (32 + hi8) ^ swl;

    const int NT = K >> 6;

    f32x4 acc[4][4] = {};
    f16x8 af[4][2], bf0[2][2], bf1[2][2];

#define PV_STAGE(TT, B)                                                        \
    do {                                                                       \
        f16* base_ = sm + (B) * 24576;                                         \
        const f16* a_ = Asrc + (size_t)(TT) * 64;                              \
        gl_lds16(a_, base_ + wst);                                             \
        gl_lds16(a_ + (size_t)64 * lda, base_ + 4096 + wst);                   \
        gl_lds16(a_ + (size_t)128 * lda, base_ + 8192 + wst);                  \
        gl_lds16(a_ + (size_t)192 * lda, base_ + 12288 + wst);                 \
        const f16* b_ = Bsrc + (size_t)(TT) * 64;                              \
        gl_lds16(b_, base_ + 16384 + wst);                                     \
        gl_lds16(b_ + (size_t)64 * ldb, base_ + 20480 + wst);                  \
    } while (0)

    PV_STAGE(0, 0);
    PV_STAGE(1, 1);
    asm volatile("s_waitcnt vmcnt(6)" ::: "memory");
    S_BARRIER();

    for (int t = 0; t < NT; ++t) {
        const int p = t & 1;
        const f16* sAp = sm + p * 24576 + wr * 4096 + fr * 64;
        const f16* sBp = sm + p * 24576 + 16384 + wc * 4096 + fr * 64;
        const bool s1 = (t + 1 < NT), s2 = (t + 2 < NT);

        // entry: ALL 16 frag reads of this tile
#pragma unroll
        for (int i = 0; i < 4; i++) {
            af[i][0] = *(const f16x8*)(sAp + i * 1024 + ca0);
            af[i][1] = *(const f16x8*)(sAp + i * 1024 + ca1);
        }
#pragma unroll
        for (int j = 0; j < 2; j++) {
            bf0[j][0] = *(const f16x8*)(sBp + j * 1024 + ca0);
            bf0[j][1] = *(const f16x8*)(sBp + j * 1024 + ca1);
        }
#pragma unroll
        for (int j = 0; j < 2; j++) {
            bf1[j][0] = *(const f16x8*)(sBp + 2048 + j * 1024 + ca0);
            bf1[j][1] = *(const f16x8*)(sBp + 2048 + j * 1024 + ca1);
        }
        asm volatile("s_waitcnt lgkmcnt(4)" ::: "memory");  // af+bf0 done
        SCHED_FENCE();
        __builtin_amdgcn_s_setprio(1);
#pragma unroll
        for (int i = 0; i < 4; i++)
#pragma unroll
            for (int j = 0; j < 2; j++) {
                acc[i][j] = __builtin_amdgcn_mfma_f32_16x16x32_f16(af[i][0], bf0[j][0], acc[i][j], 0, 0, 0);
                acc[i][j] = __builtin_amdgcn_mfma_f32_16x16x32_f16(af[i][1], bf0[j][1], acc[i][j], 0, 0, 0);
            }
        __builtin_amdgcn_s_setprio(0);
        asm volatile("s_waitcnt lgkmcnt(0)" ::: "memory");  // bf1 done
        SCHED_FENCE();
        S_BARRIER();                 // #1: all waves done reading buf p
        if (s2) {
            PV_STAGE(t + 2, p);
            asm volatile("s_waitcnt vmcnt(6)" ::: "memory"); // t+1 landed
        } else if (s1) {
            asm volatile("s_waitcnt vmcnt(0)" ::: "memory");
        }
        S_BARRIER();                 // #2: buf p^1 (t+1) visible to all
        __builtin_amdgcn_s_setprio(1);
#pragma unroll
        for (int i = 0; i < 4; i++)
#pragma unroll
            for (int j = 0; j < 2; j++) {
                acc[i][2 + j] = __builtin_amdgcn_mfma_f32_16x16x32_f16(af[i][0], bf1[j][0], acc[i][2 + j], 0, 0, 0);
                acc[i][2 + j] = __builtin_amdgcn_mfma_f32_16x16x32_f16(af[i][1], bf1[j][1], acc[i][2 + j], 0, 0, 0);
            }
        __builtin_amdgcn_s_setprio(0);
    }
#undef PV_STAGE

    const int q4 = (l >> 4) * 4;
#pragma unroll
    for (int mt = 0; mt < 4; mt++)
#pragma unroll
        for (int r = 0; r < 4; r++) {
            int row = m0 + wr * 64 + mt * 16 + q4 + r;
            float rowv = 1.f / lsum[row];
#pragma unroll
            for (int nt = 0; nt < 4; nt++) {
                int col = n0 + wc * 64 + nt * 16 + fr;
                C[(size_t)row * ldc + col] = (f16)(acc[mt][nt][r] * rowv);
            }
        }
}

// ---------------------------------------------------------------------------
// reduce per-block row partials: lsum[z][n] = sum_{j<nb} part[(z*nb+j)*n + n_i]
// grid (2*n/256), block 256.
__global__ void k_partred(const float* __restrict__ part, float* __restrict__ lsum,
                          int nb, int n)
{
    int i = blockIdx.x * 256 + threadIdx.x;
    int z = i / n, r = i - z * n;
    float s = 0.f;
    for (int j = 0; j < nb; j++) s += part[((long)z * nb + j) * n + r];
    lsum[i] = s;
}

// ---------------------------------------------------------------------------
// LayerNorm over 3584 cols of (ctx + resid), both f16, -> f16 out. grid N, block 256.
__global__ void k_layernorm(const f16* __restrict__ ctxp, const f16* __restrict__ resp,
                            const float* __restrict__ g, const float* __restrict__ be,
                            f16* __restrict__ out)
{
    long base = (long)blockIdx.x * LLM_DIM;
    const f16x8* c8 = (const f16x8*)(ctxp + base);
    const f16x8* r8 = (const f16x8*)(resp + base);
    int t = threadIdx.x, w = t >> 6, l = t & 63;
    bool has2 = t < 192;
    f16x8 a0 = c8[t], b0 = r8[t];
    f16x8 a1 = {}, b1 = {};
    if (has2) { a1 = c8[256 + t]; b1 = r8[256 + t]; }
    float v[16];
    float s = 0.f;
#pragma unroll
    for (int j = 0; j < 8; j++) { v[j] = (float)a0[j] + (float)b0[j]; s += v[j]; }
#pragma unroll
    for (int j = 0; j < 8; j++) v[8 + j] = (float)a1[j] + (float)b1[j];
    if (has2)
#pragma unroll
        for (int j = 0; j < 8; j++) s += v[8 + j];
#pragma unroll
    for (int o = 32; o; o >>= 1) s += __shfl_xor(s, o);
    __shared__ float r1[4];
    if (l == 0) r1[w] = s;
    __syncthreads();
    float mu = (r1[0] + r1[1] + r1[2] + r1[3]) * (1.f / LLM_DIM);
    float s2 = 0.f;
#pragma unroll
    for (int j = 0; j < 8; j++) { float d = v[j] - mu; s2 += d * d; }
    if (has2)
#pragma unroll
        for (int j = 8; j < 16; j++) { float d = v[j] - mu; s2 += d * d; }
#pragma unroll
    for (int o = 32; o; o >>= 1) s2 += __shfl_xor(s2, o);
    __shared__ float r2[4];
    if (l == 0) r2[w] = s2;
    __syncthreads();
    float var = (r2[0] + r2[1] + r2[2] + r2[3]) * (1.f / LLM_DIM);
    float inv = rsqrtf(var + LN_EPS);
    f16* op = out + base;
    f16x8 o0, o1;
#pragma unroll
    for (int j = 0; j < 8; j++) {
        int c = t * 8 + j;
        o0[j] = (f16)((v[j] - mu) * inv * g[c] + be[c]);
    }
    ((f16x8*)op)[t] = o0;
    if (has2) {
#pragma unroll
        for (int j = 0; j < 8; j++) {
            int c = (256 + t) * 8 + j;
            o1[j] = (f16)((v[8 + j] - mu) * inv * g[c] + be[c]);
        }
        ((f16x8*)op)[256 + t] = o1;
    }
}

// ---------------------------------------------------------------------------
extern "C" void kernel_launch(void* const* d_in, const int* in_sizes, int n_in,
                              void* d_out, int out_size, void* d_ws, size_t ws_size,
                              hipStream_t stream)
{
    const float* target  = (const float*)d_in[0];
    const float* source  = (const float*)d_in[1];
    const float* value   = (const float*)d_in[2];
    const float* wq_w    = (const float*)d_in[3];
    const float* wq_b    = (const float*)d_in[4];
    const float* wk_w    = (const float*)d_in[5];
    const float* wk_b    = (const float*)d_in[6];
    const float* wv_w    = (const float*)d_in[7];
    const float* wv_b    = (const float*)d_in[8];
    const float* resid_w = (const float*)d_in[9];
    const float* resid_b = (const float*)d_in[10];
    const float* out_w   = (const float*)d_in[11];
    const float* out_b   = (const float*)d_in[12];
    const float* ln_g    = (const float*)d_in[13];
    const float* ln_b    = (const float*)d_in[14];

    const int N = in_sizes[0] / REGION_DIM;  // 4096
    const int M = in_sizes[1] / LLM_DIM;     // 4096

    // ---- workspace: persistent ~151 MB + one 67.1 MB aliased union = ~218 MB
    char* ws = (char*)d_ws;
    size_t off = 0;
    auto alloc = [&](size_t bytes) { void* p = ws + off; off += (bytes + 255) & ~(size_t)255; return p; };
    f16*   tgt16   = (f16*)alloc((size_t)N * KPAD_REGION * 2);
    f16*   residT  = (f16*)alloc((size_t)LLM_DIM * KPAD_REGION * 2); // [3584][160]
    f16*   outT    = (f16*)alloc((size_t)LLM_DIM * LLM_DIM * 2);     // [3584][3584]
    f16*   wqT     = (f16*)alloc((size_t)QK_COLS * KPAD_REGION * 2); // [256][160]
    float* biasK   = (float*)alloc(QK_COLS * 4);
    float* biasQ   = (float*)alloc(QK_COLS * 4);
    f16*   Qtmp    = (f16*)alloc((size_t)N * QK_COLS * 2);           // [N][256]
    f16*   Ktmp    = (f16*)alloc((size_t)M * QK_COLS * 2);           // [M][256]
    f16*   Vt      = (f16*)alloc((size_t)LLM_DIM * M * 2);           // [H*896][M]
    f16*   residbf = (f16*)alloc((size_t)N * LLM_DIM * 2);           // resid proj, f16
    f16*   ctx     = (f16*)alloc((size_t)N * LLM_DIM * 2);           // attn output, f16
    f16*   xln     = (f16*)alloc((size_t)N * LLM_DIM * 2);
    float* lsum    = (float*)alloc((size_t)2 * N * 4);               // [HB][N]
    float* rowpart = (float*)alloc((size_t)2 * (M / 128) * N * 4);   // [HB][M/128][N], 1 MB
    const int HB = 2;
    char* U = (char*)alloc((size_t)HB * N * M * 2);                  // 67.1 MB
    f16* val16 = (f16*)U;
    f16* wvT   = (f16*)(U + (size_t)M * LLM_DIM * 2);
    f16* src16 = (f16*)U;
    f16* wkT   = (f16*)(U + (size_t)M * LLM_DIM * 2);
    f16* attnB = (f16*)U;
    (void)n_in; (void)out_size; (void)ws_size;

    dim3 tb(32, 8);

    // ---- phase 0: target-side prep ----
    k_convert_pad<<<dim3(1, N), 256, 0, stream>>>(target, tgt16, REGION_DIM, KPAD_REGION);
    k_transpose<<<dim3(LLM_DIM / 32, KPAD_REGION / 32, 1), tb, 0, stream>>>(
        resid_w, residT, REGION_DIM, LLM_DIM, KPAD_REGION, LLM_DIM, 0, 0);
    k_transpose<<<dim3(LLM_DIM / 32, LLM_DIM / 32, 1), tb, 0, stream>>>(
        out_w, outT, LLM_DIM, LLM_DIM, LLM_DIM, LLM_DIM, 0, 0);
    k_headpad_w<<<dim3(1, QK_COLS), 256, 0, stream>>>(wq_w, wq_b, wqT, biasQ, REGION_DIM, KPAD_REGION);

    gemm_f16<EPI_F16_BIASCOL><<<dim3(QK_COLS / 128, N / 128), 256, 0, stream>>>(
        tgt16, KPAD_REGION, 0, wqT, KPAD_REGION, 0, Qtmp, QK_COLS, 0, biasQ, 0, 1.f, KPAD_REGION, nullptr);
    gemm_f16<EPI_F16_BIASCOL><<<dim3(LLM_DIM / 128, N / 128), 256, 0, stream>>>(
        tgt16, KPAD_REGION, 0, residT, KPAD_REGION, 0, residbf, LLM_DIM, 0, resid_b, 0, 1.f, KPAD_REGION, nullptr);

    // ---- phase V: value projection (256^2 decoupled GEMM) ----
    k_convert_pad<<<dim3(LLM_DIM / 256, M), 256, 0, stream>>>(value, val16, LLM_DIM, LLM_DIM);
    k_transpose<<<dim3(V_HEAD / 32, LLM_DIM / 32, NUM_HEADS), tb, 0, stream>>>(
        wv_w, wvT, LLM_DIM, V_HEAD, LLM_DIM, V_HEAD, (long)LLM_DIM * V_HEAD, (long)V_HEAD * LLM_DIM);
    gemm256_f16<EPI_F16_BIASROW><<<dim3(M / 256, LLM_DIM / 256), 512, 0, stream>>>(
        wvT, LLM_DIM, val16, LLM_DIM, Vt, M, wv_b, LLM_DIM);

    // ---- phase K: key projection ----
    k_convert_pad<<<dim3(LLM_DIM / 256, M), 256, 0, stream>>>(source, src16, LLM_DIM, LLM_DIM);
    k_headpad_w<<<dim3(LLM_DIM / 256, QK_COLS), 256, 0, stream>>>(wk_w, wk_b, wkT, biasK, LLM_DIM, LLM_DIM);
    gemm_f16<EPI_F16_BIASCOL><<<dim3(QK_COLS / 128, M / 128), 256, 0, stream>>>(
        src16, LLM_DIM, 0, wkT, LLM_DIM, 0, Ktmp, QK_COLS, 0, biasK, 0, 1.f, LLM_DIM, nullptr);

    // ---- phase A: attention, 2 heads at a time ----
    // scores store exp(qk/6) directly; row sums fused into the exp-GEMM
    // epilogue (deterministic block partials), reduced by k_partred.
    const float sc = 0.16666667f;  // 1/sqrt(36)
    for (int h0 = 0; h0 < NUM_HEADS; h0 += HB) {
        gemm_f16<EPI_F16_EXPSUM><<<dim3(M / 128, N / 128, HB), 256, 0, stream>>>(
            Qtmp + h0 * HEAD_PAD, QK_COLS, HEAD_PAD,
            Ktmp + h0 * HEAD_PAD, QK_COLS, HEAD_PAD,
            attnB, M, (long)N * M, nullptr, 0, sc, HEAD_PAD, rowpart);
        k_partred<<<(2 * N) / 256, 256, 0, stream>>>(rowpart, lsum, M / 128, N);
        gemm_pv<<<dim3(V_HEAD / 128, N / 256, HB), 512, 0, stream>>>(
            attnB, M, (long)N * M,
            Vt + (size_t)h0 * V_HEAD * M, M, (long)V_HEAD * M,
            ctx + (size_t)h0 * V_HEAD, LLM_DIM, V_HEAD, lsum, N, M);
    }

    // ---- epilogue: LayerNorm + output projection (256^2 decoupled GEMM) ----
    k_layernorm<<<N, 256, 0, stream>>>(ctx, residbf, ln_g, ln_b, xln);
    gemm256_f16<EPI_F32_BIASCOL><<<dim3(LLM_DIM / 256, N / 256), 512, 0, stream>>>(
        xln, LLM_DIM, outT, LLM_DIM, (float*)d_out, LLM_DIM, out_b, LLM_DIM);
}